// Round 5
// baseline (491.135 us; speedup 1.0000x reference)
//
#include <hip/hip_runtime.h>
#include <stdint.h>

#define D_MODEL 1024
#define NHEADS 16
#define HDIM 64
#define CHUNK 2048
#define SEQ 8192
#define NCHUNK 4

typedef __attribute__((ext_vector_type(8))) short bf16x8;
typedef __attribute__((ext_vector_type(4))) float f32x4;

static __device__ __forceinline__ short f2bf(float f) {
    unsigned int u = __builtin_bit_cast(unsigned int, f);
    u = (u + 0x7FFFu + ((u >> 16) & 1u)) >> 16;
    return (short)u;
}

// pack two f32 -> two bf16 (round-half-up; cheap)
static __device__ __forceinline__ unsigned int pkbf(float a, float b) {
    unsigned int ua = __builtin_bit_cast(unsigned int, a) + 0x8000u;
    unsigned int ub = __builtin_bit_cast(unsigned int, b) + 0x8000u;
    return (ua >> 16) | (ub & 0xFFFF0000u);
}

static __device__ __forceinline__ void gl_lds16(const void* g, void* l) {
    __builtin_amdgcn_global_load_lds((__attribute__((address_space(1))) void*)g,
                                     (__attribute__((address_space(3))) void*)l,
                                     16, 0, 0);
}

// ---------------- fp32 -> bf16 conversion (hidden states) ----------------
__global__ void cvt_f32_bf16(const float* __restrict__ in, short* __restrict__ out, int n) {
    int i = (blockIdx.x * 256 + threadIdx.x) * 4;
    if (i >= n) return;
    float4 v = *(const float4*)(in + i);
    short4 o;
    o.x = f2bf(v.x); o.y = f2bf(v.y); o.z = f2bf(v.z); o.w = f2bf(v.w);
    *(short4*)(out + i) = o;
}

// ---------------- all four weights in one launch ----------------
// blocks [0,1024): Wq -> Wqkv[0..), [1024,2048): Wk -> +nW, [2048,3072): Wv -> +2nW,
// [3072,4096): Wo -> Wob
__global__ void cvt_w4(const float* __restrict__ Wq, const float* __restrict__ Wk,
                       const float* __restrict__ Wv, const float* __restrict__ Wo,
                       short* __restrict__ Wqkv, short* __restrict__ Wob) {
    const int nW = D_MODEL * D_MODEL;
    int b = blockIdx.x;
    int which = b >> 10;
    const float* src = (which == 0) ? Wq : (which == 1) ? Wk : (which == 2) ? Wv : Wo;
    short* dst = (which < 3) ? (Wqkv + which * nW) : Wob;
    int i = ((b & 1023) * 256 + threadIdx.x) * 4;
    float4 v = *(const float4*)(src + i);
    short4 o;
    o.x = f2bf(v.x); o.y = f2bf(v.y); o.z = f2bf(v.z); o.w = f2bf(v.w);
    *(short4*)(dst + i) = o;
}

// ---------------- fused QKV GEMM ----------------
// A [8192][1024] bf16, B = Wqkv [3072][1024] bf16 (rows: Wq | Wk | Wv).
// cols < 2048 -> QK[row][col] row-major (stride 2048).
// cols >= 2048 -> V, written TRANSPOSED into VT[((h*4+n)*64+d)*2048 + key]
//   (lane's 4 acc rows are 4 consecutive keys at fixed d -> one 8B store).
__global__ __launch_bounds__(256) void gemm_qkv(const short* __restrict__ A,
                                                const short* __restrict__ B,
                                                short* __restrict__ QK,
                                                short* __restrict__ VT) {
    __shared__ __align__(16) short As[128 * 32];
    __shared__ __align__(16) short Bs[128 * 32];
    const int tid  = threadIdx.x;
    const int lane = tid & 63;
    const int w    = tid >> 6;
    const int wr   = w >> 1, wc = w & 1;
    const int rowBase = blockIdx.y * 128;
    const int colBase = blockIdx.x * 128;
    const int quad = lane >> 4;
    const int cl   = lane & 15;
    const int K = D_MODEL;

    f32x4 acc[4][4];
    #pragma unroll
    for (int i = 0; i < 4; ++i)
        #pragma unroll
        for (int j = 0; j < 4; ++j)
            acc[i][j] = (f32x4){0.f, 0.f, 0.f, 0.f};

    const int tr = tid >> 2;
    const int tc = (tid & 3) * 8;
    const short* gA0 = A + (size_t)(rowBase + tr) * K + tc;
    const short* gA1 = A + (size_t)(rowBase + 64 + tr) * K + tc;
    const short* gB0 = B + (size_t)(colBase + tr) * K + tc;
    const short* gB1 = B + (size_t)(colBase + 64 + tr) * K + tc;

    for (int k0 = 0; k0 < K; k0 += 32) {
        gl_lds16(gA0 + k0, &As[tid * 8]);
        gl_lds16(gA1 + k0, &As[2048 + tid * 8]);
        gl_lds16(gB0 + k0, &Bs[tid * 8]);
        gl_lds16(gB1 + k0, &Bs[2048 + tid * 8]);
        __syncthreads();

        bf16x8 af[4], bfr[4];
        #pragma unroll
        for (int mi = 0; mi < 4; ++mi)
            af[mi] = *(const bf16x8*)&As[(wr * 64 + mi * 16 + cl) * 32 + quad * 8];
        #pragma unroll
        for (int ni = 0; ni < 4; ++ni)
            bfr[ni] = *(const bf16x8*)&Bs[(wc * 64 + ni * 16 + cl) * 32 + quad * 8];

        #pragma unroll
        for (int mi = 0; mi < 4; ++mi)
            #pragma unroll
            for (int ni = 0; ni < 4; ++ni)
                acc[mi][ni] = __builtin_amdgcn_mfma_f32_16x16x32_bf16(af[mi], bfr[ni], acc[mi][ni], 0, 0, 0);
        __syncthreads();
    }

    if (colBase < 2048) {
        #pragma unroll
        for (int mi = 0; mi < 4; ++mi)
            #pragma unroll
            for (int ni = 0; ni < 4; ++ni)
                #pragma unroll
                for (int r = 0; r < 4; ++r) {
                    int row = rowBase + wr * 64 + mi * 16 + quad * 4 + r;
                    int col = colBase + wc * 64 + ni * 16 + cl;
                    QK[(size_t)row * 2048 + col] = f2bf(acc[mi][ni][r]);
                }
    } else {
        #pragma unroll
        for (int mi = 0; mi < 4; ++mi) {
            int row0 = rowBase + wr * 64 + mi * 16 + quad * 4;
            int n = row0 >> 11, key = row0 & 2047;
            #pragma unroll
            for (int ni = 0; ni < 4; ++ni) {
                int c3 = colBase - 2048 + wc * 64 + ni * 16 + cl;
                int h = c3 >> 6, d = c3 & 63;
                short4 o;
                o.x = f2bf(acc[mi][ni][0]);
                o.y = f2bf(acc[mi][ni][1]);
                o.z = f2bf(acc[mi][ni][2]);
                o.w = f2bf(acc[mi][ni][3]);
                *(short4*)(VT + (size_t)((h * NCHUNK + n) * HDIM + d) * CHUNK + key) = o;
            }
        }
    }
}

// ---------------- plain GEMM for the output projection ----------------
__global__ __launch_bounds__(256) void gemm_out(const short* __restrict__ A,
                                                const short* __restrict__ B,
                                                float* __restrict__ Cout,
                                                int M, int N, int K) {
    __shared__ __align__(16) short As[128 * 32];
    __shared__ __align__(16) short Bs[128 * 32];
    const int tid  = threadIdx.x;
    const int lane = tid & 63;
    const int w    = tid >> 6;
    const int wr   = w >> 1, wc = w & 1;
    const int rowBase = blockIdx.y * 128;
    const int colBase = blockIdx.x * 128;
    const int quad = lane >> 4;
    const int cl   = lane & 15;

    f32x4 acc[4][4];
    #pragma unroll
    for (int i = 0; i < 4; ++i)
        #pragma unroll
        for (int j = 0; j < 4; ++j)
            acc[i][j] = (f32x4){0.f, 0.f, 0.f, 0.f};

    const int tr = tid >> 2;
    const int tc = (tid & 3) * 8;
    const short* gA0 = A + (size_t)(rowBase + tr) * K + tc;
    const short* gA1 = A + (size_t)(rowBase + 64 + tr) * K + tc;
    const short* gB0 = B + (size_t)(colBase + tr) * K + tc;
    const short* gB1 = B + (size_t)(colBase + 64 + tr) * K + tc;

    for (int k0 = 0; k0 < K; k0 += 32) {
        gl_lds16(gA0 + k0, &As[tid * 8]);
        gl_lds16(gA1 + k0, &As[2048 + tid * 8]);
        gl_lds16(gB0 + k0, &Bs[tid * 8]);
        gl_lds16(gB1 + k0, &Bs[2048 + tid * 8]);
        __syncthreads();

        bf16x8 af[4], bfr[4];
        #pragma unroll
        for (int mi = 0; mi < 4; ++mi)
            af[mi] = *(const bf16x8*)&As[(wr * 64 + mi * 16 + cl) * 32 + quad * 8];
        #pragma unroll
        for (int ni = 0; ni < 4; ++ni)
            bfr[ni] = *(const bf16x8*)&Bs[(wc * 64 + ni * 16 + cl) * 32 + quad * 8];

        #pragma unroll
        for (int mi = 0; mi < 4; ++mi)
            #pragma unroll
            for (int ni = 0; ni < 4; ++ni)
                acc[mi][ni] = __builtin_amdgcn_mfma_f32_16x16x32_bf16(af[mi], bfr[ni], acc[mi][ni], 0, 0, 0);
        __syncthreads();
    }

    #pragma unroll
    for (int mi = 0; mi < 4; ++mi)
        #pragma unroll
        for (int ni = 0; ni < 4; ++ni)
            #pragma unroll
            for (int r = 0; r < 4; ++r) {
                int row = rowBase + wr * 64 + mi * 16 + quad * 4 + r;
                int col = colBase + wc * 64 + ni * 16 + cl;
                Cout[(size_t)row * N + col] = acc[mi][ni][r];
            }
}

// ---------------- flash attention, chunk-local causal ----------------
// grid (16, NCHUNK, NHEADS); block 256 = 4 waves; 128 q rows/block (qi
// swizzled for balance); 128-key tiles; key perm kappa = 8*cl + kt.
// Double-buffered K/V staging in DISTINCT LDS objects (KtA/KtB, VtA/VtB) so
// the prefetch for tile t+1 overlaps compute on tile t without the compiler
// inserting a defensive vmcnt wait (distinct alias sets).
__global__ __launch_bounds__(256, 2) void attn_kernel(const short* __restrict__ QK,
                                                      const short* __restrict__ VT,
                                                      short* __restrict__ O) {
    __shared__ __align__(16) short KtA[8192];
    __shared__ __align__(16) short KtB[8192];
    __shared__ __align__(16) short VtA[8192];
    __shared__ __align__(16) short VtB[8192];
    __shared__ __align__(16) short Pt[8192];
    const int tid  = threadIdx.x;
    const int lane = tid & 63;
    const int w    = tid >> 6;
    const int quad = lane >> 4;
    const int cl   = lane & 15;
    const int h = blockIdx.z;
    const int n = blockIdx.y;
    const int qi  = (blockIdx.x + blockIdx.y + blockIdx.z) & 15;  // balance swizzle
    const int qb0 = qi * 128;
    const int s0  = qb0 + w * 32;

    const short* Qg  = QK + (size_t)n * CHUNK * 2048 + h * HDIM;          // Q cols 0..1023
    const short* Kg  = QK + (size_t)n * CHUNK * 2048 + 1024 + h * HDIM;   // K cols 1024..2047
    const short* VTg = VT + (size_t)(h * NCHUNK + n) * HDIM * CHUNK;
    short* Pw = Pt + w * 2048;

    bf16x8 qf[2][2];
    #pragma unroll
    for (int st = 0; st < 2; ++st)
        #pragma unroll
        for (int hf = 0; hf < 2; ++hf)
            qf[st][hf] = *(const bf16x8*)(Qg + (size_t)(s0 + st * 16 + cl) * 2048 + hf * 32 + quad * 8);

    bf16x8 ones;
    #pragma unroll
    for (int i = 0; i < 8; ++i) ones[i] = (short)0x3F80;

    f32x4 m4[2], l4[2], o_acc[2][4];
    #pragma unroll
    for (int st = 0; st < 2; ++st) {
        m4[st] = (f32x4){-3.0e38f, -3.0e38f, -3.0e38f, -3.0e38f};
        l4[st] = (f32x4){0.f, 0.f, 0.f, 0.f};
        #pragma unroll
        for (int dt = 0; dt < 4; ++dt) o_acc[st][dt] = (f32x4){0.f, 0.f, 0.f, 0.f};
    }

    const float cs = 0.18033688011f;  // log2(e)/sqrt(64)
    const int ntiles = qi + 1;

    auto stage_tile = [&](short* Kb, short* Vb, int t) {
        const int kb = t * 128;
        #pragma unroll
        for (int j = 0; j < 4; ++j) {
            int s = j * 256 + tid;
            int row = s >> 3;
            int c = (s & 7) ^ ((row >> 3) & 7);
            gl_lds16(Kg + (size_t)(kb + row) * 2048 + c * 8, Kb + s * 8);
        }
        #pragma unroll
        for (int j = 0; j < 4; ++j) {
            int s = j * 256 + tid;
            int d = s >> 4;
            int c = (s & 15) ^ (d & 15);
            gl_lds16(VTg + (size_t)d * CHUNK + kb + c * 8, Vb + s * 8);
        }
    };

    auto compute_tile = [&](const short* Kb, const short* Vb, int t) {
        const int kb = t * 128;
        const bool full = (t < qi);
        #pragma unroll
        for (int st = 0; st < 2; ++st) {
            const int sb = s0 + st * 16;
            f32x4 sa[8];
            #pragma unroll
            for (int kt = 0; kt < 8; ++kt) {
                int row = 8 * cl + kt;
                bf16x8 k0 = *(const bf16x8*)(Kb + (row * 8 + (quad ^ (cl & 7))) * 8);
                bf16x8 k1 = *(const bf16x8*)(Kb + (row * 8 + ((4 + quad) ^ (cl & 7))) * 8);
                sa[kt] = (f32x4){0.f, 0.f, 0.f, 0.f};
                sa[kt] = __builtin_amdgcn_mfma_f32_16x16x32_bf16(qf[st][0], k0, sa[kt], 0, 0, 0);
                sa[kt] = __builtin_amdgcn_mfma_f32_16x16x32_bf16(qf[st][1], k1, sa[kt], 0, 0, 0);
            }
            if (!full) {
                int k8 = kb + 8 * cl;
                #pragma unroll
                for (int r = 0; r < 4; ++r) {
                    int q = sb + quad * 4 + r;
                    #pragma unroll
                    for (int kt = 0; kt < 8; ++kt)
                        if (k8 + kt > q) sa[kt][r] = -3.0e38f;
                }
            }
            f32x4 mx = sa[0];
            #pragma unroll
            for (int kt = 1; kt < 8; ++kt)
                #pragma unroll
                for (int r = 0; r < 4; ++r) mx[r] = fmaxf(mx[r], sa[kt][r]);
            #pragma unroll
            for (int r = 0; r < 4; ++r) {
                float m = mx[r];
                m = fmaxf(m, __shfl_xor(m, 1));
                m = fmaxf(m, __shfl_xor(m, 2));
                m = fmaxf(m, __shfl_xor(m, 4));
                m = fmaxf(m, __shfl_xor(m, 8));
                mx[r] = m;
            }
            f32x4 alpha, nm;
            #pragma unroll
            for (int r = 0; r < 4; ++r) {
                float mnew = fmaxf(m4[st][r], mx[r]);
                alpha[r] = __builtin_amdgcn_exp2f((m4[st][r] - mnew) * cs);
                nm[r] = mnew * cs;
                m4[st][r] = mnew;
            }
            #pragma unroll
            for (int r = 0; r < 4; ++r) l4[st][r] *= alpha[r];
            #pragma unroll
            for (int dt = 0; dt < 4; ++dt)
                #pragma unroll
                for (int r = 0; r < 4; ++r) o_acc[st][dt][r] *= alpha[r];
            #pragma unroll
            for (int r = 0; r < 4; ++r) {
                float p0 = __builtin_amdgcn_exp2f(__builtin_fmaf(sa[0][r], cs, -nm[r]));
                float p1 = __builtin_amdgcn_exp2f(__builtin_fmaf(sa[1][r], cs, -nm[r]));
                float p2 = __builtin_amdgcn_exp2f(__builtin_fmaf(sa[2][r], cs, -nm[r]));
                float p3 = __builtin_amdgcn_exp2f(__builtin_fmaf(sa[3][r], cs, -nm[r]));
                float p4 = __builtin_amdgcn_exp2f(__builtin_fmaf(sa[4][r], cs, -nm[r]));
                float p5 = __builtin_amdgcn_exp2f(__builtin_fmaf(sa[5][r], cs, -nm[r]));
                float p6 = __builtin_amdgcn_exp2f(__builtin_fmaf(sa[6][r], cs, -nm[r]));
                float p7 = __builtin_amdgcn_exp2f(__builtin_fmaf(sa[7][r], cs, -nm[r]));
                uint4 pk;
                pk.x = pkbf(p0, p1);
                pk.y = pkbf(p2, p3);
                pk.z = pkbf(p4, p5);
                pk.w = pkbf(p6, p7);
                int m = quad * 4 + r;
                *(uint4*)(Pw + (m * 16 + (cl ^ m)) * 8) = pk;
            }
            bf16x8 pf[4];
            #pragma unroll
            for (int kc = 0; kc < 4; ++kc)
                pf[kc] = *(const bf16x8*)(Pw + (cl * 16 + ((kc * 4 + quad) ^ cl)) * 8);
            f32x4 rs = (f32x4){0.f, 0.f, 0.f, 0.f};
            #pragma unroll
            for (int kc = 0; kc < 4; ++kc)
                rs = __builtin_amdgcn_mfma_f32_16x16x32_bf16(pf[kc], ones, rs, 0, 0, 0);
            #pragma unroll
            for (int r = 0; r < 4; ++r) l4[st][r] += rs[r];
            #pragma unroll
            for (int dt = 0; dt < 4; ++dt) {
                #pragma unroll
                for (int kc = 0; kc < 4; ++kc) {
                    int d = dt * 16 + cl;
                    int slot = d * 16 + ((kc * 4 + quad) ^ (d & 15));
                    bf16x8 vf = *(const bf16x8*)(Vb + slot * 8);
                    o_acc[st][dt] = __builtin_amdgcn_mfma_f32_16x16x32_bf16(pf[kc], vf, o_acc[st][dt], 0, 0, 0);
                }
            }
        }
    };

    stage_tile(KtA, VtA, 0);
    for (int t = 0; t < ntiles; t += 2) {
        __syncthreads();  // drains vmcnt -> buf A staged; all waves past prior reads
        if (t + 1 < ntiles) stage_tile(KtB, VtB, t + 1);  // prefetch overlaps compute
        compute_tile(KtA, VtA, t);
        if (t + 1 >= ntiles) break;
        __syncthreads();
        if (t + 2 < ntiles) stage_tile(KtA, VtA, t + 2);
        compute_tile(KtB, VtB, t + 1);
    }

    // epilogue: O/l -> bf16 store
    #pragma unroll
    for (int st = 0; st < 2; ++st) {
        f32x4 linv;
        #pragma unroll
        for (int r = 0; r < 4; ++r) linv[r] = __builtin_amdgcn_rcpf(l4[st][r]);
        #pragma unroll
        for (int dt = 0; dt < 4; ++dt)
            #pragma unroll
            for (int r = 0; r < 4; ++r) {
                float val = o_acc[st][dt][r] * linv[r];
                size_t row = (size_t)n * CHUNK + s0 + st * 16 + quad * 4 + r;
                O[row * D_MODEL + h * HDIM + dt * 16 + cl] = f2bf(val);
            }
    }
}

extern "C" void kernel_launch(void* const* d_in, const int* in_sizes, int n_in,
                              void* d_out, int out_size, void* d_ws, size_t ws_size,
                              hipStream_t stream) {
    const float* hs = (const float*)d_in[0];
    const float* Wq = (const float*)d_in[1];
    const float* Wk = (const float*)d_in[2];
    const float* Wv = (const float*)d_in[3];
    const float* Wo = (const float*)d_in[4];
    float* out = (float*)d_out;

    char* ws = (char*)d_ws;
    const size_t MB = 1024 * 1024;
    short* Xbf  = (short*)(ws);              // 16 MB  [8192][1024]
    short* QKb  = (short*)(ws + 16 * MB);    // 32 MB  [8192][2048]  (Q | K)
    short* VT   = (short*)(ws + 48 * MB);    // 16 MB  [h][n][d][key]
    short* Abf  = (short*)(ws + 64 * MB);    // 16 MB  [8192][1024]
    short* Wqkv = (short*)(ws + 80 * MB);    //  6 MB  [3072][1024]
    short* Wob  = (short*)(ws + 86 * MB);    //  2 MB

    const int nHS = SEQ * D_MODEL;
    cvt_f32_bf16<<<nHS / 1024, 256, 0, stream>>>(hs, Xbf, nHS);
    cvt_w4<<<4096, 256, 0, stream>>>(Wq, Wk, Wv, Wo, Wqkv, Wob);

    gemm_qkv<<<dim3(24, 64), 256, 0, stream>>>(Xbf, Wqkv, QKb, VT);

    attn_kernel<<<dim3(16, NCHUNK, NHEADS), 256, 0, stream>>>(QKb, VT, Abf);

    gemm_out<<<dim3(8, 64), 256, 0, stream>>>(Abf, Wob, out, SEQ, D_MODEL, D_MODEL);
}

// Round 6
// 427.310 us; speedup vs baseline: 1.1494x; 1.1494x over previous
//
#include <hip/hip_runtime.h>
#include <stdint.h>

#define D_MODEL 1024
#define NHEADS 16
#define HDIM 64
#define CHUNK 2048
#define SEQ 8192
#define NCHUNK 4

typedef __attribute__((ext_vector_type(8))) short bf16x8;
typedef __attribute__((ext_vector_type(4))) float f32x4;

static __device__ __forceinline__ short f2bf(float f) {
    unsigned int u = __builtin_bit_cast(unsigned int, f);
    u = (u + 0x7FFFu + ((u >> 16) & 1u)) >> 16;
    return (short)u;
}

// pack two f32 -> two bf16 (round-half-up; cheap)
static __device__ __forceinline__ unsigned int pkbf(float a, float b) {
    unsigned int ua = __builtin_bit_cast(unsigned int, a) + 0x8000u;
    unsigned int ub = __builtin_bit_cast(unsigned int, b) + 0x8000u;
    return (ua >> 16) | (ub & 0xFFFF0000u);
}

static __device__ __forceinline__ void gl_lds16(const void* g, void* l) {
    __builtin_amdgcn_global_load_lds((__attribute__((address_space(1))) void*)g,
                                     (__attribute__((address_space(3))) void*)l,
                                     16, 0, 0);
}

// ---------------- fp32 -> bf16 conversion (hidden states) ----------------
__global__ void cvt_f32_bf16(const float* __restrict__ in, short* __restrict__ out, int n) {
    int i = (blockIdx.x * 256 + threadIdx.x) * 4;
    if (i >= n) return;
    float4 v = *(const float4*)(in + i);
    short4 o;
    o.x = f2bf(v.x); o.y = f2bf(v.y); o.z = f2bf(v.z); o.w = f2bf(v.w);
    *(short4*)(out + i) = o;
}

// ---------------- all four weights in one launch ----------------
__global__ void cvt_w4(const float* __restrict__ Wq, const float* __restrict__ Wk,
                       const float* __restrict__ Wv, const float* __restrict__ Wo,
                       short* __restrict__ Wqkv, short* __restrict__ Wob) {
    const int nW = D_MODEL * D_MODEL;
    int b = blockIdx.x;
    int which = b >> 10;
    const float* src = (which == 0) ? Wq : (which == 1) ? Wk : (which == 2) ? Wv : Wo;
    short* dst = (which < 3) ? (Wqkv + which * nW) : Wob;
    int i = ((b & 1023) * 256 + threadIdx.x) * 4;
    float4 v = *(const float4*)(src + i);
    short4 o;
    o.x = f2bf(v.x); o.y = f2bf(v.y); o.z = f2bf(v.z); o.w = f2bf(v.w);
    *(short4*)(dst + i) = o;
}

// ---------------- fused QKV GEMM ----------------
// A [8192][1024] bf16, B = Wqkv [3072][1024] bf16 (rows: Wq | Wk | Wv).
// cols < 2048 -> QK[row][col] row-major (stride 2048).
// cols >= 2048 -> V, written TRANSPOSED into VT[((h*4+n)*64+d)*2048 + key].
__global__ __launch_bounds__(256) void gemm_qkv(const short* __restrict__ A,
                                                const short* __restrict__ B,
                                                short* __restrict__ QK,
                                                short* __restrict__ VT) {
    __shared__ __align__(16) short As[128 * 32];
    __shared__ __align__(16) short Bs[128 * 32];
    const int tid  = threadIdx.x;
    const int lane = tid & 63;
    const int w    = tid >> 6;
    const int wr   = w >> 1, wc = w & 1;
    const int rowBase = blockIdx.y * 128;
    const int colBase = blockIdx.x * 128;
    const int quad = lane >> 4;
    const int cl   = lane & 15;
    const int K = D_MODEL;

    f32x4 acc[4][4];
    #pragma unroll
    for (int i = 0; i < 4; ++i)
        #pragma unroll
        for (int j = 0; j < 4; ++j)
            acc[i][j] = (f32x4){0.f, 0.f, 0.f, 0.f};

    const int tr = tid >> 2;
    const int tc = (tid & 3) * 8;
    const short* gA0 = A + (size_t)(rowBase + tr) * K + tc;
    const short* gA1 = A + (size_t)(rowBase + 64 + tr) * K + tc;
    const short* gB0 = B + (size_t)(colBase + tr) * K + tc;
    const short* gB1 = B + (size_t)(colBase + 64 + tr) * K + tc;

    for (int k0 = 0; k0 < K; k0 += 32) {
        gl_lds16(gA0 + k0, &As[tid * 8]);
        gl_lds16(gA1 + k0, &As[2048 + tid * 8]);
        gl_lds16(gB0 + k0, &Bs[tid * 8]);
        gl_lds16(gB1 + k0, &Bs[2048 + tid * 8]);
        __syncthreads();

        bf16x8 af[4], bfr[4];
        #pragma unroll
        for (int mi = 0; mi < 4; ++mi)
            af[mi] = *(const bf16x8*)&As[(wr * 64 + mi * 16 + cl) * 32 + quad * 8];
        #pragma unroll
        for (int ni = 0; ni < 4; ++ni)
            bfr[ni] = *(const bf16x8*)&Bs[(wc * 64 + ni * 16 + cl) * 32 + quad * 8];

        #pragma unroll
        for (int mi = 0; mi < 4; ++mi)
            #pragma unroll
            for (int ni = 0; ni < 4; ++ni)
                acc[mi][ni] = __builtin_amdgcn_mfma_f32_16x16x32_bf16(af[mi], bfr[ni], acc[mi][ni], 0, 0, 0);
        __syncthreads();
    }

    if (colBase < 2048) {
        #pragma unroll
        for (int mi = 0; mi < 4; ++mi)
            #pragma unroll
            for (int ni = 0; ni < 4; ++ni)
                #pragma unroll
                for (int r = 0; r < 4; ++r) {
                    int row = rowBase + wr * 64 + mi * 16 + quad * 4 + r;
                    int col = colBase + wc * 64 + ni * 16 + cl;
                    QK[(size_t)row * 2048 + col] = f2bf(acc[mi][ni][r]);
                }
    } else {
        #pragma unroll
        for (int mi = 0; mi < 4; ++mi) {
            int row0 = rowBase + wr * 64 + mi * 16 + quad * 4;
            int n = row0 >> 11, key = row0 & 2047;
            #pragma unroll
            for (int ni = 0; ni < 4; ++ni) {
                int c3 = colBase - 2048 + wc * 64 + ni * 16 + cl;
                int h = c3 >> 6, d = c3 & 63;
                short4 o;
                o.x = f2bf(acc[mi][ni][0]);
                o.y = f2bf(acc[mi][ni][1]);
                o.z = f2bf(acc[mi][ni][2]);
                o.w = f2bf(acc[mi][ni][3]);
                *(short4*)(VT + (size_t)((h * NCHUNK + n) * HDIM + d) * CHUNK + key) = o;
            }
        }
    }
}

// ---------------- plain GEMM for the output projection ----------------
__global__ __launch_bounds__(256) void gemm_out(const short* __restrict__ A,
                                                const short* __restrict__ B,
                                                float* __restrict__ Cout,
                                                int M, int N, int K) {
    __shared__ __align__(16) short As[128 * 32];
    __shared__ __align__(16) short Bs[128 * 32];
    const int tid  = threadIdx.x;
    const int lane = tid & 63;
    const int w    = tid >> 6;
    const int wr   = w >> 1, wc = w & 1;
    const int rowBase = blockIdx.y * 128;
    const int colBase = blockIdx.x * 128;
    const int quad = lane >> 4;
    const int cl   = lane & 15;

    f32x4 acc[4][4];
    #pragma unroll
    for (int i = 0; i < 4; ++i)
        #pragma unroll
        for (int j = 0; j < 4; ++j)
            acc[i][j] = (f32x4){0.f, 0.f, 0.f, 0.f};

    const int tr = tid >> 2;
    const int tc = (tid & 3) * 8;
    const short* gA0 = A + (size_t)(rowBase + tr) * K + tc;
    const short* gA1 = A + (size_t)(rowBase + 64 + tr) * K + tc;
    const short* gB0 = B + (size_t)(colBase + tr) * K + tc;
    const short* gB1 = B + (size_t)(colBase + 64 + tr) * K + tc;

    for (int k0 = 0; k0 < K; k0 += 32) {
        gl_lds16(gA0 + k0, &As[tid * 8]);
        gl_lds16(gA1 + k0, &As[2048 + tid * 8]);
        gl_lds16(gB0 + k0, &Bs[tid * 8]);
        gl_lds16(gB1 + k0, &Bs[2048 + tid * 8]);
        __syncthreads();

        bf16x8 af[4], bfr[4];
        #pragma unroll
        for (int mi = 0; mi < 4; ++mi)
            af[mi] = *(const bf16x8*)&As[(wr * 64 + mi * 16 + cl) * 32 + quad * 8];
        #pragma unroll
        for (int ni = 0; ni < 4; ++ni)
            bfr[ni] = *(const bf16x8*)&Bs[(wc * 64 + ni * 16 + cl) * 32 + quad * 8];

        #pragma unroll
        for (int mi = 0; mi < 4; ++mi)
            #pragma unroll
            for (int ni = 0; ni < 4; ++ni)
                acc[mi][ni] = __builtin_amdgcn_mfma_f32_16x16x32_bf16(af[mi], bfr[ni], acc[mi][ni], 0, 0, 0);
        __syncthreads();
    }

    #pragma unroll
    for (int mi = 0; mi < 4; ++mi)
        #pragma unroll
        for (int ni = 0; ni < 4; ++ni)
            #pragma unroll
            for (int r = 0; r < 4; ++r) {
                int row = rowBase + wr * 64 + mi * 16 + quad * 4 + r;
                int col = colBase + wc * 64 + ni * 16 + cl;
                Cout[(size_t)row * N + col] = acc[mi][ni][r];
            }
}

// ---------------- flash attention, chunk-local causal ----------------
// grid (16, NCHUNK, NHEADS); block 256 = 4 waves; 128 q rows/block (qi
// swizzled for balance); 128-key tiles; key perm kappa = 8*cl + kt.
// REGISTER-prefetch double buffering: tile t+1's K/V loaded into 32 VGPRs
// during compute(t); ds_write'd into the (single) LDS tile at the barrier.
// Keeps R4's LDS footprint (48KB -> 3 blocks/CU) and short live ranges —
// the lambda/dual-LDS variants (R3/R5) spilled to scratch (WRITE_SIZE blew up).
__global__ __launch_bounds__(256, 2) void attn_kernel(const short* __restrict__ QK,
                                                      const short* __restrict__ VT,
                                                      short* __restrict__ O) {
    __shared__ __align__(16) short Kt[8192];  // [row 0..127][8B chunks] slot=row*8+(c^((row>>3)&7))
    __shared__ __align__(16) short Vt[8192];  // [d 0..63][16 chunks]    slot=d*16+(c^(d&15))
    __shared__ __align__(16) short Pt[8192];  // per-wave 16x128 strip-P slot=m*16+(c^m)
    const int tid  = threadIdx.x;
    const int lane = tid & 63;
    const int w    = tid >> 6;
    const int quad = lane >> 4;
    const int cl   = lane & 15;
    const int h = blockIdx.z;
    const int n = blockIdx.y;
    const int qi  = (blockIdx.x + blockIdx.y + blockIdx.z) & 15;  // balance swizzle
    const int qb0 = qi * 128;
    const int s0  = qb0 + w * 32;

    const short* Qg  = QK + (size_t)n * CHUNK * 2048 + h * HDIM;          // Q cols 0..1023
    const short* Kg  = QK + (size_t)n * CHUNK * 2048 + 1024 + h * HDIM;   // K cols 1024..2047
    const short* VTg = VT + (size_t)(h * NCHUNK + n) * HDIM * CHUNK;
    short* Pw = Pt + w * 2048;

    // per-thread staging offsets (relative to tile base)
    int offk[4], offv[4];
    #pragma unroll
    for (int j = 0; j < 4; ++j) {
        int s = j * 256 + tid;
        int row = s >> 3;
        int ck = (s & 7) ^ ((row >> 3) & 7);
        offk[j] = row * 2048 + ck * 8;
        int d = s >> 4;
        int cv = (s & 15) ^ (d & 15);
        offv[j] = d * CHUNK + cv * 8;
    }

    bf16x8 qf[2][2];
    #pragma unroll
    for (int st = 0; st < 2; ++st)
        #pragma unroll
        for (int hf = 0; hf < 2; ++hf)
            qf[st][hf] = *(const bf16x8*)(Qg + (size_t)(s0 + st * 16 + cl) * 2048 + hf * 32 + quad * 8);

    bf16x8 ones;
    #pragma unroll
    for (int i = 0; i < 8; ++i) ones[i] = (short)0x3F80;

    f32x4 m4[2], l4[2], o_acc[2][4];
    #pragma unroll
    for (int st = 0; st < 2; ++st) {
        m4[st] = (f32x4){-3.0e38f, -3.0e38f, -3.0e38f, -3.0e38f};
        l4[st] = (f32x4){0.f, 0.f, 0.f, 0.f};
        #pragma unroll
        for (int dt = 0; dt < 4; ++dt) o_acc[st][dt] = (f32x4){0.f, 0.f, 0.f, 0.f};
    }

    const float cs = 0.18033688011f;  // log2(e)/sqrt(64)
    const int ntiles = qi + 1;

    // prefetch tile 0 into registers
    uint4 kreg[4], vreg[4];
    #pragma unroll
    for (int j = 0; j < 4; ++j) {
        kreg[j] = *(const uint4*)(Kg + offk[j]);
        vreg[j] = *(const uint4*)(VTg + offv[j]);
    }

    for (int t = 0; t < ntiles; ++t) {
        const int kb = t * 128;
        __syncthreads();  // all waves done reading the previous tile's LDS
        // commit prefetched tile t to LDS (waits vmcnt on kreg/vreg only)
        #pragma unroll
        for (int j = 0; j < 4; ++j) {
            *(uint4*)(Kt + (j * 256 + tid) * 8) = kreg[j];
            *(uint4*)(Vt + (j * 256 + tid) * 8) = vreg[j];
        }
        // issue prefetch for tile t+1 (covered by compute below)
        if (t + 1 < ntiles) {
            const short* Kb2 = Kg + (size_t)(kb + 128) * 2048;
            const short* Vb2 = VTg + (kb + 128);
            #pragma unroll
            for (int j = 0; j < 4; ++j) {
                kreg[j] = *(const uint4*)(Kb2 + offk[j]);
                vreg[j] = *(const uint4*)(Vb2 + offv[j]);
            }
        }
        __syncthreads();  // LDS writes visible (lgkm drain only — cheap)

        const bool full = (t < qi);  // only the last tile is diagonal/masked

        #pragma unroll
        for (int st = 0; st < 2; ++st) {
            const int sb = s0 + st * 16;
            // ---- S = Q K^T (keys permuted: col (kt,cl) = key 8*cl+kt) ----
            f32x4 sa[8];
            #pragma unroll
            for (int kt = 0; kt < 8; ++kt) {
                int row = 8 * cl + kt;
                bf16x8 k0 = *(const bf16x8*)(Kt + (row * 8 + (quad ^ (cl & 7))) * 8);
                bf16x8 k1 = *(const bf16x8*)(Kt + (row * 8 + ((4 + quad) ^ (cl & 7))) * 8);
                sa[kt] = (f32x4){0.f, 0.f, 0.f, 0.f};
                sa[kt] = __builtin_amdgcn_mfma_f32_16x16x32_bf16(qf[st][0], k0, sa[kt], 0, 0, 0);
                sa[kt] = __builtin_amdgcn_mfma_f32_16x16x32_bf16(qf[st][1], k1, sa[kt], 0, 0, 0);
            }
            if (!full) {
                int k8 = kb + 8 * cl;
                #pragma unroll
                for (int r = 0; r < 4; ++r) {
                    int q = sb + quad * 4 + r;
                    #pragma unroll
                    for (int kt = 0; kt < 8; ++kt)
                        if (k8 + kt > q) sa[kt][r] = -3.0e38f;
                }
            }
            // ---- online softmax ----
            f32x4 mx;
            #pragma unroll
            for (int r = 0; r < 4; ++r)
                mx[r] = fmaxf(fmaxf(fmaxf(sa[0][r], sa[1][r]), fmaxf(sa[2][r], sa[3][r])),
                              fmaxf(fmaxf(sa[4][r], sa[5][r]), fmaxf(sa[6][r], sa[7][r])));
            #pragma unroll
            for (int r = 0; r < 4; ++r) {
                float m = mx[r];
                m = fmaxf(m, __shfl_xor(m, 1));
                m = fmaxf(m, __shfl_xor(m, 2));
                m = fmaxf(m, __shfl_xor(m, 4));
                m = fmaxf(m, __shfl_xor(m, 8));
                mx[r] = m;
            }
            f32x4 alpha, nm;
            #pragma unroll
            for (int r = 0; r < 4; ++r) {
                float mnew = fmaxf(m4[st][r], mx[r]);
                alpha[r] = __builtin_amdgcn_exp2f((m4[st][r] - mnew) * cs);
                nm[r] = mnew * cs;
                m4[st][r] = mnew;
            }
            #pragma unroll
            for (int r = 0; r < 4; ++r) l4[st][r] *= alpha[r];
            #pragma unroll
            for (int dt = 0; dt < 4; ++dt)
                #pragma unroll
                for (int r = 0; r < 4; ++r) o_acc[st][dt][r] *= alpha[r];
            #pragma unroll
            for (int r = 0; r < 4; ++r) {
                float p0 = __builtin_amdgcn_exp2f(__builtin_fmaf(sa[0][r], cs, -nm[r]));
                float p1 = __builtin_amdgcn_exp2f(__builtin_fmaf(sa[1][r], cs, -nm[r]));
                float p2 = __builtin_amdgcn_exp2f(__builtin_fmaf(sa[2][r], cs, -nm[r]));
                float p3 = __builtin_amdgcn_exp2f(__builtin_fmaf(sa[3][r], cs, -nm[r]));
                float p4 = __builtin_amdgcn_exp2f(__builtin_fmaf(sa[4][r], cs, -nm[r]));
                float p5 = __builtin_amdgcn_exp2f(__builtin_fmaf(sa[5][r], cs, -nm[r]));
                float p6 = __builtin_amdgcn_exp2f(__builtin_fmaf(sa[6][r], cs, -nm[r]));
                float p7 = __builtin_amdgcn_exp2f(__builtin_fmaf(sa[7][r], cs, -nm[r]));
                uint4 pk;
                pk.x = pkbf(p0, p1);
                pk.y = pkbf(p2, p3);
                pk.z = pkbf(p4, p5);
                pk.w = pkbf(p6, p7);
                int m = quad * 4 + r;
                *(uint4*)(Pw + (m * 16 + (cl ^ m)) * 8) = pk;
            }
            bf16x8 pf[4];
            #pragma unroll
            for (int kc = 0; kc < 4; ++kc)
                pf[kc] = *(const bf16x8*)(Pw + (cl * 16 + ((kc * 4 + quad) ^ cl)) * 8);
            f32x4 rs = (f32x4){0.f, 0.f, 0.f, 0.f};
            #pragma unroll
            for (int kc = 0; kc < 4; ++kc)
                rs = __builtin_amdgcn_mfma_f32_16x16x32_bf16(pf[kc], ones, rs, 0, 0, 0);
            #pragma unroll
            for (int r = 0; r < 4; ++r) l4[st][r] += rs[r];
            #pragma unroll
            for (int dt = 0; dt < 4; ++dt) {
                #pragma unroll
                for (int kc = 0; kc < 4; ++kc) {
                    int d = dt * 16 + cl;
                    int slot = d * 16 + ((kc * 4 + quad) ^ (d & 15));
                    bf16x8 vf = *(const bf16x8*)(Vt + slot * 8);
                    o_acc[st][dt] = __builtin_amdgcn_mfma_f32_16x16x32_bf16(pf[kc], vf, o_acc[st][dt], 0, 0, 0);
                }
            }
        }
    }

    // epilogue: O/l -> bf16 store
    #pragma unroll
    for (int st = 0; st < 2; ++st) {
        f32x4 linv;
        #pragma unroll
        for (int r = 0; r < 4; ++r) linv[r] = __builtin_amdgcn_rcpf(l4[st][r]);
        #pragma unroll
        for (int dt = 0; dt < 4; ++dt)
            #pragma unroll
            for (int r = 0; r < 4; ++r) {
                float val = o_acc[st][dt][r] * linv[r];
                size_t row = (size_t)n * CHUNK + s0 + st * 16 + quad * 4 + r;
                O[row * D_MODEL + h * HDIM + dt * 16 + cl] = f2bf(val);
            }
    }
}

extern "C" void kernel_launch(void* const* d_in, const int* in_sizes, int n_in,
                              void* d_out, int out_size, void* d_ws, size_t ws_size,
                              hipStream_t stream) {
    const float* hs = (const float*)d_in[0];
    const float* Wq = (const float*)d_in[1];
    const float* Wk = (const float*)d_in[2];
    const float* Wv = (const float*)d_in[3];
    const float* Wo = (const float*)d_in[4];
    float* out = (float*)d_out;

    char* ws = (char*)d_ws;
    const size_t MB = 1024 * 1024;
    short* Xbf  = (short*)(ws);              // 16 MB  [8192][1024]
    short* QKb  = (short*)(ws + 16 * MB);    // 32 MB  [8192][2048]  (Q | K)
    short* VT   = (short*)(ws + 48 * MB);    // 16 MB  [h][n][d][key]
    short* Abf  = (short*)(ws + 64 * MB);    // 16 MB  [8192][1024]
    short* Wqkv = (short*)(ws + 80 * MB);    //  6 MB  [3072][1024]
    short* Wob  = (short*)(ws + 86 * MB);    //  2 MB

    const int nHS = SEQ * D_MODEL;
    cvt_f32_bf16<<<nHS / 1024, 256, 0, stream>>>(hs, Xbf, nHS);
    cvt_w4<<<4096, 256, 0, stream>>>(Wq, Wk, Wv, Wo, Wqkv, Wob);

    gemm_qkv<<<dim3(24, 64), 256, 0, stream>>>(Xbf, Wqkv, QKb, VT);

    attn_kernel<<<dim3(16, NCHUNK, NHEADS), 256, 0, stream>>>(QKb, VT, Abf);

    gemm_out<<<dim3(8, 64), 256, 0, stream>>>(Abf, Wob, out, SEQ, D_MODEL, D_MODEL);
}

// Round 7
// 329.117 us; speedup vs baseline: 1.4923x; 1.2984x over previous
//
#include <hip/hip_runtime.h>
#include <stdint.h>

#define D_MODEL 1024
#define NHEADS 16
#define HDIM 64
#define CHUNK 2048
#define SEQ 8192
#define NCHUNK 4

typedef __attribute__((ext_vector_type(8))) short bf16x8;
typedef __attribute__((ext_vector_type(4))) float f32x4;

static __device__ __forceinline__ short f2bf(float f) {
    unsigned int u = __builtin_bit_cast(unsigned int, f);
    u = (u + 0x7FFFu + ((u >> 16) & 1u)) >> 16;
    return (short)u;
}

// pack two f32 -> two bf16 (round-half-up; cheap)
static __device__ __forceinline__ unsigned int pkbf(float a, float b) {
    unsigned int ua = __builtin_bit_cast(unsigned int, a) + 0x8000u;
    unsigned int ub = __builtin_bit_cast(unsigned int, b) + 0x8000u;
    return (ua >> 16) | (ub & 0xFFFF0000u);
}

static __device__ __forceinline__ void gl_lds16(const void* g, void* l) {
    __builtin_amdgcn_global_load_lds((__attribute__((address_space(1))) void*)g,
                                     (__attribute__((address_space(3))) void*)l,
                                     16, 0, 0);
}

// ---------------- fp32 -> bf16 conversion (hidden states) ----------------
__global__ void cvt_f32_bf16(const float* __restrict__ in, short* __restrict__ out, int n) {
    int i = (blockIdx.x * 256 + threadIdx.x) * 4;
    if (i >= n) return;
    float4 v = *(const float4*)(in + i);
    short4 o;
    o.x = f2bf(v.x); o.y = f2bf(v.y); o.z = f2bf(v.z); o.w = f2bf(v.w);
    *(short4*)(out + i) = o;
}

// ---------------- all four weights in one launch ----------------
__global__ void cvt_w4(const float* __restrict__ Wq, const float* __restrict__ Wk,
                       const float* __restrict__ Wv, const float* __restrict__ Wo,
                       short* __restrict__ Wqkv, short* __restrict__ Wob) {
    const int nW = D_MODEL * D_MODEL;
    int b = blockIdx.x;
    int which = b >> 10;
    const float* src = (which == 0) ? Wq : (which == 1) ? Wk : (which == 2) ? Wv : Wo;
    short* dst = (which < 3) ? (Wqkv + which * nW) : Wob;
    int i = ((b & 1023) * 256 + threadIdx.x) * 4;
    float4 v = *(const float4*)(src + i);
    short4 o;
    o.x = f2bf(v.x); o.y = f2bf(v.y); o.z = f2bf(v.z); o.w = f2bf(v.w);
    *(short4*)(dst + i) = o;
}

// ---------------- fused QKV GEMM ----------------
// A [8192][1024] bf16, B = Wqkv [3072][1024] bf16 (rows: Wq | Wk | Wv).
// cols < 2048 -> QK[row][col] row-major (stride 2048).
// cols >= 2048 -> V, written TRANSPOSED into VT[((h*4+n)*64+d)*2048 + key].
__global__ __launch_bounds__(256) void gemm_qkv(const short* __restrict__ A,
                                                const short* __restrict__ B,
                                                short* __restrict__ QK,
                                                short* __restrict__ VT) {
    __shared__ __align__(16) short As[128 * 32];
    __shared__ __align__(16) short Bs[128 * 32];
    const int tid  = threadIdx.x;
    const int lane = tid & 63;
    const int w    = tid >> 6;
    const int wr   = w >> 1, wc = w & 1;
    const int rowBase = blockIdx.y * 128;
    const int colBase = blockIdx.x * 128;
    const int quad = lane >> 4;
    const int cl   = lane & 15;
    const int K = D_MODEL;

    f32x4 acc[4][4];
    #pragma unroll
    for (int i = 0; i < 4; ++i)
        #pragma unroll
        for (int j = 0; j < 4; ++j)
            acc[i][j] = (f32x4){0.f, 0.f, 0.f, 0.f};

    const int tr = tid >> 2;
    const int tc = (tid & 3) * 8;
    const short* gA0 = A + (size_t)(rowBase + tr) * K + tc;
    const short* gA1 = A + (size_t)(rowBase + 64 + tr) * K + tc;
    const short* gB0 = B + (size_t)(colBase + tr) * K + tc;
    const short* gB1 = B + (size_t)(colBase + 64 + tr) * K + tc;

    for (int k0 = 0; k0 < K; k0 += 32) {
        gl_lds16(gA0 + k0, &As[tid * 8]);
        gl_lds16(gA1 + k0, &As[2048 + tid * 8]);
        gl_lds16(gB0 + k0, &Bs[tid * 8]);
        gl_lds16(gB1 + k0, &Bs[2048 + tid * 8]);
        __syncthreads();

        bf16x8 af[4], bfr[4];
        #pragma unroll
        for (int mi = 0; mi < 4; ++mi)
            af[mi] = *(const bf16x8*)&As[(wr * 64 + mi * 16 + cl) * 32 + quad * 8];
        #pragma unroll
        for (int ni = 0; ni < 4; ++ni)
            bfr[ni] = *(const bf16x8*)&Bs[(wc * 64 + ni * 16 + cl) * 32 + quad * 8];

        #pragma unroll
        for (int mi = 0; mi < 4; ++mi)
            #pragma unroll
            for (int ni = 0; ni < 4; ++ni)
                acc[mi][ni] = __builtin_amdgcn_mfma_f32_16x16x32_bf16(af[mi], bfr[ni], acc[mi][ni], 0, 0, 0);
        __syncthreads();
    }

    if (colBase < 2048) {
        #pragma unroll
        for (int mi = 0; mi < 4; ++mi)
            #pragma unroll
            for (int ni = 0; ni < 4; ++ni)
                #pragma unroll
                for (int r = 0; r < 4; ++r) {
                    int row = rowBase + wr * 64 + mi * 16 + quad * 4 + r;
                    int col = colBase + wc * 64 + ni * 16 + cl;
                    QK[(size_t)row * 2048 + col] = f2bf(acc[mi][ni][r]);
                }
    } else {
        #pragma unroll
        for (int mi = 0; mi < 4; ++mi) {
            int row0 = rowBase + wr * 64 + mi * 16 + quad * 4;
            int n = row0 >> 11, key = row0 & 2047;
            #pragma unroll
            for (int ni = 0; ni < 4; ++ni) {
                int c3 = colBase - 2048 + wc * 64 + ni * 16 + cl;
                int h = c3 >> 6, d = c3 & 63;
                short4 o;
                o.x = f2bf(acc[mi][ni][0]);
                o.y = f2bf(acc[mi][ni][1]);
                o.z = f2bf(acc[mi][ni][2]);
                o.w = f2bf(acc[mi][ni][3]);
                *(short4*)(VT + (size_t)((h * NCHUNK + n) * HDIM + d) * CHUNK + key) = o;
            }
        }
    }
}

// ---------------- plain GEMM for the output projection ----------------
__global__ __launch_bounds__(256) void gemm_out(const short* __restrict__ A,
                                                const short* __restrict__ B,
                                                float* __restrict__ Cout,
                                                int M, int N, int K) {
    __shared__ __align__(16) short As[128 * 32];
    __shared__ __align__(16) short Bs[128 * 32];
    const int tid  = threadIdx.x;
    const int lane = tid & 63;
    const int w    = tid >> 6;
    const int wr   = w >> 1, wc = w & 1;
    const int rowBase = blockIdx.y * 128;
    const int colBase = blockIdx.x * 128;
    const int quad = lane >> 4;
    const int cl   = lane & 15;

    f32x4 acc[4][4];
    #pragma unroll
    for (int i = 0; i < 4; ++i)
        #pragma unroll
        for (int j = 0; j < 4; ++j)
            acc[i][j] = (f32x4){0.f, 0.f, 0.f, 0.f};

    const int tr = tid >> 2;
    const int tc = (tid & 3) * 8;
    const short* gA0 = A + (size_t)(rowBase + tr) * K + tc;
    const short* gA1 = A + (size_t)(rowBase + 64 + tr) * K + tc;
    const short* gB0 = B + (size_t)(colBase + tr) * K + tc;
    const short* gB1 = B + (size_t)(colBase + 64 + tr) * K + tc;

    for (int k0 = 0; k0 < K; k0 += 32) {
        gl_lds16(gA0 + k0, &As[tid * 8]);
        gl_lds16(gA1 + k0, &As[2048 + tid * 8]);
        gl_lds16(gB0 + k0, &Bs[tid * 8]);
        gl_lds16(gB1 + k0, &Bs[2048 + tid * 8]);
        __syncthreads();

        bf16x8 af[4], bfr[4];
        #pragma unroll
        for (int mi = 0; mi < 4; ++mi)
            af[mi] = *(const bf16x8*)&As[(wr * 64 + mi * 16 + cl) * 32 + quad * 8];
        #pragma unroll
        for (int ni = 0; ni < 4; ++ni)
            bfr[ni] = *(const bf16x8*)&Bs[(wc * 64 + ni * 16 + cl) * 32 + quad * 8];

        #pragma unroll
        for (int mi = 0; mi < 4; ++mi)
            #pragma unroll
            for (int ni = 0; ni < 4; ++ni)
                acc[mi][ni] = __builtin_amdgcn_mfma_f32_16x16x32_bf16(af[mi], bfr[ni], acc[mi][ni], 0, 0, 0);
        __syncthreads();
    }

    #pragma unroll
    for (int mi = 0; mi < 4; ++mi)
        #pragma unroll
        for (int ni = 0; ni < 4; ++ni)
            #pragma unroll
            for (int r = 0; r < 4; ++r) {
                int row = rowBase + wr * 64 + mi * 16 + quad * 4 + r;
                int col = colBase + wc * 64 + ni * 16 + cl;
                Cout[(size_t)row * N + col] = acc[mi][ni][r];
            }
}

// ---------------- flash attention, chunk-local causal ----------------
// EXACT R4 structure (measured 127 us, WRITE_SIZE 16 MB, no spills):
// single LDS buffer, gl_lds staging, two barriers/tile, no values held
// live across the compute body. Only the input addressing differs (QK
// fused buffer stride 2048; V pre-transposed by gemm_qkv).
// DO NOT add prefetch/double-buffer here: R3/R5/R6 all spilled to scratch
// (WRITE_SIZE 128-346 MB) because any long live range crosses the cliff.
__global__ __launch_bounds__(256, 2) void attn_kernel(const short* __restrict__ QK,
                                                      const short* __restrict__ VT,
                                                      short* __restrict__ O) {
    __shared__ __align__(16) short Kt[8192];  // [row 0..127][8B chunks] slot=row*8+(c^((row>>3)&7))
    __shared__ __align__(16) short Vt[8192];  // [d 0..63][16 chunks]    slot=d*16+(c^(d&15))
    __shared__ __align__(16) short Pt[8192];  // per-wave 16x128 strip-P slot=m*16+(c^m)
    const int tid  = threadIdx.x;
    const int lane = tid & 63;
    const int w    = tid >> 6;
    const int quad = lane >> 4;
    const int cl   = lane & 15;
    const int h = blockIdx.z;
    const int n = blockIdx.y;
    const int qi  = (blockIdx.x + blockIdx.y + blockIdx.z) & 15;  // balance swizzle
    const int qb0 = qi * 128;
    const int s0  = qb0 + w * 32;

    const short* Qg  = QK + (size_t)n * CHUNK * 2048 + h * HDIM;          // Q cols 0..1023
    const short* Kg  = QK + (size_t)n * CHUNK * 2048 + 1024 + h * HDIM;   // K cols 1024..2047
    const short* VTg = VT + (size_t)(h * NCHUNK + n) * HDIM * CHUNK;
    short* Pw = Pt + w * 2048;

    bf16x8 qf[2][2];
    #pragma unroll
    for (int st = 0; st < 2; ++st)
        #pragma unroll
        for (int hf = 0; hf < 2; ++hf)
            qf[st][hf] = *(const bf16x8*)(Qg + (size_t)(s0 + st * 16 + cl) * 2048 + hf * 32 + quad * 8);

    bf16x8 ones;
    #pragma unroll
    for (int i = 0; i < 8; ++i) ones[i] = (short)0x3F80;

    f32x4 m4[2], l4[2], o_acc[2][4];
    #pragma unroll
    for (int st = 0; st < 2; ++st) {
        m4[st] = (f32x4){-3.0e38f, -3.0e38f, -3.0e38f, -3.0e38f};
        l4[st] = (f32x4){0.f, 0.f, 0.f, 0.f};
        #pragma unroll
        for (int dt = 0; dt < 4; ++dt) o_acc[st][dt] = (f32x4){0.f, 0.f, 0.f, 0.f};
    }

    const float cs = 0.18033688011f;  // log2(e)/sqrt(64)
    const int ntiles = qi + 1;

    for (int t = 0; t < ntiles; ++t) {
        const int kb = t * 128;
        __syncthreads();  // all waves done reading prev tile
        #pragma unroll
        for (int j = 0; j < 4; ++j) {
            int s = j * 256 + tid;
            int row = s >> 3;
            int c = (s & 7) ^ ((row >> 3) & 7);
            gl_lds16(Kg + (size_t)(kb + row) * 2048 + c * 8, Kt + s * 8);
        }
        #pragma unroll
        for (int j = 0; j < 4; ++j) {
            int s = j * 256 + tid;
            int d = s >> 4;
            int c = (s & 15) ^ (d & 15);
            gl_lds16(VTg + (size_t)d * CHUNK + kb + c * 8, Vt + s * 8);
        }
        __syncthreads();  // staged data visible (vmcnt drained)

        const bool full = (t < qi);  // only the last tile is diagonal/masked

        #pragma unroll
        for (int st = 0; st < 2; ++st) {
            const int sb = s0 + st * 16;
            // ---- S = Q K^T (keys permuted: col (kt,cl) = key 8*cl+kt) ----
            f32x4 sa[8];
            #pragma unroll
            for (int kt = 0; kt < 8; ++kt) {
                int row = 8 * cl + kt;
                bf16x8 k0 = *(const bf16x8*)(Kt + (row * 8 + (quad ^ (cl & 7))) * 8);
                bf16x8 k1 = *(const bf16x8*)(Kt + (row * 8 + ((4 + quad) ^ (cl & 7))) * 8);
                sa[kt] = (f32x4){0.f, 0.f, 0.f, 0.f};
                sa[kt] = __builtin_amdgcn_mfma_f32_16x16x32_bf16(qf[st][0], k0, sa[kt], 0, 0, 0);
                sa[kt] = __builtin_amdgcn_mfma_f32_16x16x32_bf16(qf[st][1], k1, sa[kt], 0, 0, 0);
            }
            if (!full) {
                int k8 = kb + 8 * cl;
                #pragma unroll
                for (int r = 0; r < 4; ++r) {
                    int q = sb + quad * 4 + r;
                    #pragma unroll
                    for (int kt = 0; kt < 8; ++kt)
                        if (k8 + kt > q) sa[kt][r] = -3.0e38f;
                }
            }
            // ---- online softmax ----
            f32x4 mx;
            #pragma unroll
            for (int r = 0; r < 4; ++r)
                mx[r] = fmaxf(fmaxf(fmaxf(sa[0][r], sa[1][r]), fmaxf(sa[2][r], sa[3][r])),
                              fmaxf(fmaxf(sa[4][r], sa[5][r]), fmaxf(sa[6][r], sa[7][r])));
            #pragma unroll
            for (int r = 0; r < 4; ++r) {
                float m = mx[r];
                m = fmaxf(m, __shfl_xor(m, 1));
                m = fmaxf(m, __shfl_xor(m, 2));
                m = fmaxf(m, __shfl_xor(m, 4));
                m = fmaxf(m, __shfl_xor(m, 8));
                mx[r] = m;
            }
            f32x4 alpha, nm;
            #pragma unroll
            for (int r = 0; r < 4; ++r) {
                float mnew = fmaxf(m4[st][r], mx[r]);
                alpha[r] = __builtin_amdgcn_exp2f((m4[st][r] - mnew) * cs);
                nm[r] = mnew * cs;
                m4[st][r] = mnew;
            }
            #pragma unroll
            for (int r = 0; r < 4; ++r) l4[st][r] *= alpha[r];
            #pragma unroll
            for (int dt = 0; dt < 4; ++dt)
                #pragma unroll
                for (int r = 0; r < 4; ++r) o_acc[st][dt][r] *= alpha[r];
            #pragma unroll
            for (int r = 0; r < 4; ++r) {
                float p0 = __builtin_amdgcn_exp2f(__builtin_fmaf(sa[0][r], cs, -nm[r]));
                float p1 = __builtin_amdgcn_exp2f(__builtin_fmaf(sa[1][r], cs, -nm[r]));
                float p2 = __builtin_amdgcn_exp2f(__builtin_fmaf(sa[2][r], cs, -nm[r]));
                float p3 = __builtin_amdgcn_exp2f(__builtin_fmaf(sa[3][r], cs, -nm[r]));
                float p4 = __builtin_amdgcn_exp2f(__builtin_fmaf(sa[4][r], cs, -nm[r]));
                float p5 = __builtin_amdgcn_exp2f(__builtin_fmaf(sa[5][r], cs, -nm[r]));
                float p6 = __builtin_amdgcn_exp2f(__builtin_fmaf(sa[6][r], cs, -nm[r]));
                float p7 = __builtin_amdgcn_exp2f(__builtin_fmaf(sa[7][r], cs, -nm[r]));
                uint4 pk;
                pk.x = pkbf(p0, p1);
                pk.y = pkbf(p2, p3);
                pk.z = pkbf(p4, p5);
                pk.w = pkbf(p6, p7);
                int m = quad * 4 + r;
                *(uint4*)(Pw + (m * 16 + (cl ^ m)) * 8) = pk;
            }
            bf16x8 pf[4];
            #pragma unroll
            for (int kc = 0; kc < 4; ++kc)
                pf[kc] = *(const bf16x8*)(Pw + (cl * 16 + ((kc * 4 + quad) ^ cl)) * 8);
            f32x4 rs = (f32x4){0.f, 0.f, 0.f, 0.f};
            #pragma unroll
            for (int kc = 0; kc < 4; ++kc)
                rs = __builtin_amdgcn_mfma_f32_16x16x32_bf16(pf[kc], ones, rs, 0, 0, 0);
            #pragma unroll
            for (int r = 0; r < 4; ++r) l4[st][r] += rs[r];
            #pragma unroll
            for (int dt = 0; dt < 4; ++dt) {
                #pragma unroll
                for (int kc = 0; kc < 4; ++kc) {
                    int d = dt * 16 + cl;
                    int slot = d * 16 + ((kc * 4 + quad) ^ (d & 15));
                    bf16x8 vf = *(const bf16x8*)(Vt + slot * 8);
                    o_acc[st][dt] = __builtin_amdgcn_mfma_f32_16x16x32_bf16(pf[kc], vf, o_acc[st][dt], 0, 0, 0);
                }
            }
        }
    }

    // epilogue: O/l -> bf16 store
    #pragma unroll
    for (int st = 0; st < 2; ++st) {
        f32x4 linv;
        #pragma unroll
        for (int r = 0; r < 4; ++r) linv[r] = __builtin_amdgcn_rcpf(l4[st][r]);
        #pragma unroll
        for (int dt = 0; dt < 4; ++dt)
            #pragma unroll
            for (int r = 0; r < 4; ++r) {
                float val = o_acc[st][dt][r] * linv[r];
                size_t row = (size_t)n * CHUNK + s0 + st * 16 + quad * 4 + r;
                O[row * D_MODEL + h * HDIM + dt * 16 + cl] = f2bf(val);
            }
    }
}

extern "C" void kernel_launch(void* const* d_in, const int* in_sizes, int n_in,
                              void* d_out, int out_size, void* d_ws, size_t ws_size,
                              hipStream_t stream) {
    const float* hs = (const float*)d_in[0];
    const float* Wq = (const float*)d_in[1];
    const float* Wk = (const float*)d_in[2];
    const float* Wv = (const float*)d_in[3];
    const float* Wo = (const float*)d_in[4];
    float* out = (float*)d_out;

    char* ws = (char*)d_ws;
    const size_t MB = 1024 * 1024;
    short* Xbf  = (short*)(ws);              // 16 MB  [8192][1024]
    short* QKb  = (short*)(ws + 16 * MB);    // 32 MB  [8192][2048]  (Q | K)
    short* VT   = (short*)(ws + 48 * MB);    // 16 MB  [h][n][d][key]
    short* Abf  = (short*)(ws + 64 * MB);    // 16 MB  [8192][1024]
    short* Wqkv = (short*)(ws + 80 * MB);    //  6 MB  [3072][1024]
    short* Wob  = (short*)(ws + 86 * MB);    //  2 MB

    const int nHS = SEQ * D_MODEL;
    cvt_f32_bf16<<<nHS / 1024, 256, 0, stream>>>(hs, Xbf, nHS);
    cvt_w4<<<4096, 256, 0, stream>>>(Wq, Wk, Wv, Wo, Wqkv, Wob);

    gemm_qkv<<<dim3(24, 64), 256, 0, stream>>>(Xbf, Wqkv, QKb, VT);

    attn_kernel<<<dim3(16, NCHUNK, NHEADS), 256, 0, stream>>>(QKb, VT, Abf);

    gemm_out<<<dim3(8, 64), 256, 0, stream>>>(Abf, Wob, out, SEQ, D_MODEL, D_MODEL);
}

// Round 8
// 309.476 us; speedup vs baseline: 1.5870x; 1.0635x over previous
//
#include <hip/hip_runtime.h>
#include <stdint.h>

#define D_MODEL 1024
#define NHEADS 16
#define HDIM 64
#define CHUNK 2048
#define SEQ 8192
#define NCHUNK 4

typedef __attribute__((ext_vector_type(8))) short bf16x8;
typedef __attribute__((ext_vector_type(4))) float f32x4;

static __device__ __forceinline__ short f2bf(float f) {
    unsigned int u = __builtin_bit_cast(unsigned int, f);
    u = (u + 0x7FFFu + ((u >> 16) & 1u)) >> 16;
    return (short)u;
}

static __device__ __forceinline__ unsigned int pkbf(float a, float b) {
    unsigned int ua = __builtin_bit_cast(unsigned int, a) + 0x8000u;
    unsigned int ub = __builtin_bit_cast(unsigned int, b) + 0x8000u;
    return (ua >> 16) | (ub & 0xFFFF0000u);
}

static __device__ __forceinline__ void gl_lds16(const void* g, void* l) {
    __builtin_amdgcn_global_load_lds((__attribute__((address_space(1))) void*)g,
                                     (__attribute__((address_space(3))) void*)l,
                                     16, 0, 0);
}

// ---------------- fp32 -> bf16 conversion (hidden states) ----------------
__global__ void cvt_f32_bf16(const float* __restrict__ in, short* __restrict__ out, int n) {
    int i = (blockIdx.x * 256 + threadIdx.x) * 4;
    if (i >= n) return;
    float4 v = *(const float4*)(in + i);
    short4 o;
    o.x = f2bf(v.x); o.y = f2bf(v.y); o.z = f2bf(v.z); o.w = f2bf(v.w);
    *(short4*)(out + i) = o;
}

// ---------------- all four weights in one launch ----------------
__global__ void cvt_w4(const float* __restrict__ Wq, const float* __restrict__ Wk,
                       const float* __restrict__ Wv, const float* __restrict__ Wo,
                       short* __restrict__ Wqkv, short* __restrict__ Wob) {
    const int nW = D_MODEL * D_MODEL;
    int b = blockIdx.x;
    int which = b >> 10;
    const float* src = (which == 0) ? Wq : (which == 1) ? Wk : (which == 2) ? Wv : Wo;
    short* dst = (which < 3) ? (Wqkv + which * nW) : Wob;
    int i = ((b & 1023) * 256 + threadIdx.x) * 4;
    float4 v = *(const float4*)(src + i);
    short4 o;
    o.x = f2bf(v.x); o.y = f2bf(v.y); o.z = f2bf(v.z); o.w = f2bf(v.w);
    *(short4*)(dst + i) = o;
}

// ---------------- fused QKV GEMM, BK=64 ----------------
// A [8192][1024] bf16, B = Wqkv [3072][1024] bf16 (rows: Wq | Wk | Wv).
// BK=64 halves barrier count vs BK=32 (K=1024 -> 16 iters). LDS k-dim is
// XOR-swizzled (kc8 ^ (row&7)) applied to the gl_lds SOURCE address (dest
// must stay wave-linear), giving m97's conflict-free ds_read_b128 profile.
// cols < 2048 -> QK[row][col] row-major (stride 2048).
// cols >= 2048 -> V, written TRANSPOSED into VT[((h*4+n)*64+d)*2048 + key].
__global__ __launch_bounds__(256) void gemm_qkv(const short* __restrict__ A,
                                                const short* __restrict__ B,
                                                short* __restrict__ QK,
                                                short* __restrict__ VT) {
    __shared__ __align__(16) short As[128 * 64];
    __shared__ __align__(16) short Bs[128 * 64];
    const int tid  = threadIdx.x;
    const int lane = tid & 63;
    const int w    = tid >> 6;
    const int wr   = w >> 1, wc = w & 1;
    const int rowBase = blockIdx.y * 128;
    const int colBase = blockIdx.x * 128;
    const int quad = lane >> 4;
    const int cl   = lane & 15;
    const int K = D_MODEL;

    f32x4 acc[4][4];
    #pragma unroll
    for (int i = 0; i < 4; ++i)
        #pragma unroll
        for (int j = 0; j < 4; ++j)
            acc[i][j] = (f32x4){0.f, 0.f, 0.f, 0.f};

    // staging: s = j*256+tid -> row = s>>3, kc8 = s&7; source k-chunk swizzled
    int srow[4], skc[4];
    #pragma unroll
    for (int j = 0; j < 4; ++j) {
        int s = j * 256 + tid;
        srow[j] = s >> 3;
        skc[j]  = ((s & 7) ^ (srow[j] & 7)) * 8;
    }

    for (int k0 = 0; k0 < K; k0 += 64) {
        #pragma unroll
        for (int j = 0; j < 4; ++j) {
            gl_lds16(A + (size_t)(rowBase + srow[j]) * K + k0 + skc[j], &As[(j * 256 + tid) * 8]);
            gl_lds16(B + (size_t)(colBase + srow[j]) * K + k0 + skc[j], &Bs[(j * 256 + tid) * 8]);
        }
        __syncthreads();

        #pragma unroll
        for (int hf = 0; hf < 2; ++hf) {
            bf16x8 af[4], bfr[4];
            #pragma unroll
            for (int mi = 0; mi < 4; ++mi) {
                int row = wr * 64 + mi * 16 + cl;
                af[mi] = *(const bf16x8*)&As[row * 64 + (((hf * 4 + quad) ^ (cl & 7)) * 8)];
            }
            #pragma unroll
            for (int ni = 0; ni < 4; ++ni) {
                int row = wc * 64 + ni * 16 + cl;
                bfr[ni] = *(const bf16x8*)&Bs[row * 64 + (((hf * 4 + quad) ^ (cl & 7)) * 8)];
            }
            #pragma unroll
            for (int mi = 0; mi < 4; ++mi)
                #pragma unroll
                for (int ni = 0; ni < 4; ++ni)
                    acc[mi][ni] = __builtin_amdgcn_mfma_f32_16x16x32_bf16(af[mi], bfr[ni], acc[mi][ni], 0, 0, 0);
        }
        __syncthreads();
    }

    if (colBase < 2048) {
        #pragma unroll
        for (int mi = 0; mi < 4; ++mi)
            #pragma unroll
            for (int ni = 0; ni < 4; ++ni)
                #pragma unroll
                for (int r = 0; r < 4; ++r) {
                    int row = rowBase + wr * 64 + mi * 16 + quad * 4 + r;
                    int col = colBase + wc * 64 + ni * 16 + cl;
                    QK[(size_t)row * 2048 + col] = f2bf(acc[mi][ni][r]);
                }
    } else {
        #pragma unroll
        for (int mi = 0; mi < 4; ++mi) {
            int row0 = rowBase + wr * 64 + mi * 16 + quad * 4;
            int n = row0 >> 11, key = row0 & 2047;
            #pragma unroll
            for (int ni = 0; ni < 4; ++ni) {
                int c3 = colBase - 2048 + wc * 64 + ni * 16 + cl;
                int h = c3 >> 6, d = c3 & 63;
                short4 o;
                o.x = f2bf(acc[mi][ni][0]);
                o.y = f2bf(acc[mi][ni][1]);
                o.z = f2bf(acc[mi][ni][2]);
                o.w = f2bf(acc[mi][ni][3]);
                *(short4*)(VT + (size_t)((h * NCHUNK + n) * HDIM + d) * CHUNK + key) = o;
            }
        }
    }
}

// ---------------- output projection GEMM, BK=64 (same structure) ----------------
__global__ __launch_bounds__(256) void gemm_out(const short* __restrict__ A,
                                                const short* __restrict__ B,
                                                float* __restrict__ Cout,
                                                int M, int N, int K) {
    __shared__ __align__(16) short As[128 * 64];
    __shared__ __align__(16) short Bs[128 * 64];
    const int tid  = threadIdx.x;
    const int lane = tid & 63;
    const int w    = tid >> 6;
    const int wr   = w >> 1, wc = w & 1;
    const int rowBase = blockIdx.y * 128;
    const int colBase = blockIdx.x * 128;
    const int quad = lane >> 4;
    const int cl   = lane & 15;

    f32x4 acc[4][4];
    #pragma unroll
    for (int i = 0; i < 4; ++i)
        #pragma unroll
        for (int j = 0; j < 4; ++j)
            acc[i][j] = (f32x4){0.f, 0.f, 0.f, 0.f};

    int srow[4], skc[4];
    #pragma unroll
    for (int j = 0; j < 4; ++j) {
        int s = j * 256 + tid;
        srow[j] = s >> 3;
        skc[j]  = ((s & 7) ^ (srow[j] & 7)) * 8;
    }

    for (int k0 = 0; k0 < K; k0 += 64) {
        #pragma unroll
        for (int j = 0; j < 4; ++j) {
            gl_lds16(A + (size_t)(rowBase + srow[j]) * K + k0 + skc[j], &As[(j * 256 + tid) * 8]);
            gl_lds16(B + (size_t)(colBase + srow[j]) * K + k0 + skc[j], &Bs[(j * 256 + tid) * 8]);
        }
        __syncthreads();

        #pragma unroll
        for (int hf = 0; hf < 2; ++hf) {
            bf16x8 af[4], bfr[4];
            #pragma unroll
            for (int mi = 0; mi < 4; ++mi) {
                int row = wr * 64 + mi * 16 + cl;
                af[mi] = *(const bf16x8*)&As[row * 64 + (((hf * 4 + quad) ^ (cl & 7)) * 8)];
            }
            #pragma unroll
            for (int ni = 0; ni < 4; ++ni) {
                int row = wc * 64 + ni * 16 + cl;
                bfr[ni] = *(const bf16x8*)&Bs[row * 64 + (((hf * 4 + quad) ^ (cl & 7)) * 8)];
            }
            #pragma unroll
            for (int mi = 0; mi < 4; ++mi)
                #pragma unroll
                for (int ni = 0; ni < 4; ++ni)
                    acc[mi][ni] = __builtin_amdgcn_mfma_f32_16x16x32_bf16(af[mi], bfr[ni], acc[mi][ni], 0, 0, 0);
        }
        __syncthreads();
    }

    #pragma unroll
    for (int mi = 0; mi < 4; ++mi)
        #pragma unroll
        for (int ni = 0; ni < 4; ++ni)
            #pragma unroll
            for (int r = 0; r < 4; ++r) {
                int row = rowBase + wr * 64 + mi * 16 + quad * 4 + r;
                int col = colBase + wc * 64 + ni * 16 + cl;
                Cout[(size_t)row * N + col] = acc[mi][ni][r];
            }
}

// ---------------- flash attention, chunk-local causal ----------------
// R7 compute body, but dual LDS K/V buffers with ONE barrier per tile:
// after the barrier, issue gl_lds prefetch for tile t+1 into the OTHER
// buffer, then compute tile t. The next barrier's vmcnt(0) drain lands a
// full compute-phase after issue -> drain is free. NO register-carried
// state added (the R3/R5/R6 spill mechanism was long float live ranges;
// here only two LDS base pointers cross the compute body).
__global__ __launch_bounds__(256, 2) void attn_kernel(const short* __restrict__ QK,
                                                      const short* __restrict__ VT,
                                                      short* __restrict__ O) {
    __shared__ __align__(16) short KV[2][16384];  // [buf][ K:0..8191 | V:8192..16383 ]
    __shared__ __align__(16) short Pt[8192];      // per-wave 16x128 strip-P slot=m*16+(c^m)
    const int tid  = threadIdx.x;
    const int lane = tid & 63;
    const int w    = tid >> 6;
    const int quad = lane >> 4;
    const int cl   = lane & 15;
    const int h = blockIdx.z;
    const int n = blockIdx.y;
    const int qi  = (blockIdx.x + blockIdx.y + blockIdx.z) & 15;  // balance swizzle
    const int qb0 = qi * 128;
    const int s0  = qb0 + w * 32;

    const short* Qg  = QK + (size_t)n * CHUNK * 2048 + h * HDIM;          // Q cols 0..1023
    const short* Kg  = QK + (size_t)n * CHUNK * 2048 + 1024 + h * HDIM;   // K cols 1024..2047
    const short* VTg = VT + (size_t)(h * NCHUNK + n) * HDIM * CHUNK;
    short* Pw = Pt + w * 2048;

    bf16x8 qf[2][2];
    #pragma unroll
    for (int st = 0; st < 2; ++st)
        #pragma unroll
        for (int hf = 0; hf < 2; ++hf)
            qf[st][hf] = *(const bf16x8*)(Qg + (size_t)(s0 + st * 16 + cl) * 2048 + hf * 32 + quad * 8);

    bf16x8 ones;
    #pragma unroll
    for (int i = 0; i < 8; ++i) ones[i] = (short)0x3F80;

    f32x4 m4[2], l4[2], o_acc[2][4];
    #pragma unroll
    for (int st = 0; st < 2; ++st) {
        m4[st] = (f32x4){-3.0e38f, -3.0e38f, -3.0e38f, -3.0e38f};
        l4[st] = (f32x4){0.f, 0.f, 0.f, 0.f};
        #pragma unroll
        for (int dt = 0; dt < 4; ++dt) o_acc[st][dt] = (f32x4){0.f, 0.f, 0.f, 0.f};
    }

    const float cs = 0.18033688011f;  // log2(e)/sqrt(64)
    const int ntiles = qi + 1;

    // prologue: stage tile 0 into buf 0
    #pragma unroll
    for (int j = 0; j < 4; ++j) {
        int s = j * 256 + tid;
        int row = s >> 3;
        int c = (s & 7) ^ ((row >> 3) & 7);
        gl_lds16(Kg + (size_t)row * 2048 + c * 8, &KV[0][s * 8]);
    }
    #pragma unroll
    for (int j = 0; j < 4; ++j) {
        int s = j * 256 + tid;
        int d = s >> 4;
        int c = (s & 15) ^ (d & 15);
        gl_lds16(VTg + (size_t)d * CHUNK + c * 8, &KV[0][8192 + s * 8]);
    }

    for (int t = 0; t < ntiles; ++t) {
        const int kb = t * 128;
        __syncthreads();  // drains vmcnt: tile t staged; all waves done reading other buf
        // prefetch tile t+1 into the other buffer (overlaps compute below)
        if (t + 1 < ntiles) {
            short* nb = KV[(t + 1) & 1];
            const int kb2 = kb + 128;
            #pragma unroll
            for (int j = 0; j < 4; ++j) {
                int s = j * 256 + tid;
                int row = s >> 3;
                int c = (s & 7) ^ ((row >> 3) & 7);
                gl_lds16(Kg + (size_t)(kb2 + row) * 2048 + c * 8, nb + s * 8);
            }
            #pragma unroll
            for (int j = 0; j < 4; ++j) {
                int s = j * 256 + tid;
                int d = s >> 4;
                int c = (s & 15) ^ (d & 15);
                gl_lds16(VTg + (size_t)d * CHUNK + kb2 + c * 8, nb + 8192 + s * 8);
            }
        }
        const short* Kt = KV[t & 1];
        const short* Vt = KV[t & 1] + 8192;

        const bool full = (t < qi);  // only the last tile is diagonal/masked

        #pragma unroll
        for (int st = 0; st < 2; ++st) {
            const int sb = s0 + st * 16;
            // ---- S = Q K^T (keys permuted: col (kt,cl) = key 8*cl+kt) ----
            f32x4 sa[8];
            #pragma unroll
            for (int kt = 0; kt < 8; ++kt) {
                int row = 8 * cl + kt;
                bf16x8 k0 = *(const bf16x8*)(Kt + (row * 8 + (quad ^ (cl & 7))) * 8);
                bf16x8 k1 = *(const bf16x8*)(Kt + (row * 8 + ((4 + quad) ^ (cl & 7))) * 8);
                sa[kt] = (f32x4){0.f, 0.f, 0.f, 0.f};
                sa[kt] = __builtin_amdgcn_mfma_f32_16x16x32_bf16(qf[st][0], k0, sa[kt], 0, 0, 0);
                sa[kt] = __builtin_amdgcn_mfma_f32_16x16x32_bf16(qf[st][1], k1, sa[kt], 0, 0, 0);
            }
            if (!full) {
                int k8 = kb + 8 * cl;
                #pragma unroll
                for (int r = 0; r < 4; ++r) {
                    int q = sb + quad * 4 + r;
                    #pragma unroll
                    for (int kt = 0; kt < 8; ++kt)
                        if (k8 + kt > q) sa[kt][r] = -3.0e38f;
                }
            }
            // ---- online softmax ----
            f32x4 mx;
            #pragma unroll
            for (int r = 0; r < 4; ++r)
                mx[r] = fmaxf(fmaxf(fmaxf(sa[0][r], sa[1][r]), fmaxf(sa[2][r], sa[3][r])),
                              fmaxf(fmaxf(sa[4][r], sa[5][r]), fmaxf(sa[6][r], sa[7][r])));
            #pragma unroll
            for (int r = 0; r < 4; ++r) {
                float m = mx[r];
                m = fmaxf(m, __shfl_xor(m, 1));
                m = fmaxf(m, __shfl_xor(m, 2));
                m = fmaxf(m, __shfl_xor(m, 4));
                m = fmaxf(m, __shfl_xor(m, 8));
                mx[r] = m;
            }
            f32x4 alpha, nm;
            #pragma unroll
            for (int r = 0; r < 4; ++r) {
                float mnew = fmaxf(m4[st][r], mx[r]);
                alpha[r] = __builtin_amdgcn_exp2f((m4[st][r] - mnew) * cs);
                nm[r] = mnew * cs;
                m4[st][r] = mnew;
            }
            #pragma unroll
            for (int r = 0; r < 4; ++r) l4[st][r] *= alpha[r];
            #pragma unroll
            for (int dt = 0; dt < 4; ++dt)
                #pragma unroll
                for (int r = 0; r < 4; ++r) o_acc[st][dt][r] *= alpha[r];
            #pragma unroll
            for (int r = 0; r < 4; ++r) {
                float p0 = __builtin_amdgcn_exp2f(__builtin_fmaf(sa[0][r], cs, -nm[r]));
                float p1 = __builtin_amdgcn_exp2f(__builtin_fmaf(sa[1][r], cs, -nm[r]));
                float p2 = __builtin_amdgcn_exp2f(__builtin_fmaf(sa[2][r], cs, -nm[r]));
                float p3 = __builtin_amdgcn_exp2f(__builtin_fmaf(sa[3][r], cs, -nm[r]));
                float p4 = __builtin_amdgcn_exp2f(__builtin_fmaf(sa[4][r], cs, -nm[r]));
                float p5 = __builtin_amdgcn_exp2f(__builtin_fmaf(sa[5][r], cs, -nm[r]));
                float p6 = __builtin_amdgcn_exp2f(__builtin_fmaf(sa[6][r], cs, -nm[r]));
                float p7 = __builtin_amdgcn_exp2f(__builtin_fmaf(sa[7][r], cs, -nm[r]));
                uint4 pk;
                pk.x = pkbf(p0, p1);
                pk.y = pkbf(p2, p3);
                pk.z = pkbf(p4, p5);
                pk.w = pkbf(p6, p7);
                int m = quad * 4 + r;
                *(uint4*)(Pw + (m * 16 + (cl ^ m)) * 8) = pk;
            }
            bf16x8 pf[4];
            #pragma unroll
            for (int kc = 0; kc < 4; ++kc)
                pf[kc] = *(const bf16x8*)(Pw + (cl * 16 + ((kc * 4 + quad) ^ cl)) * 8);
            f32x4 rs = (f32x4){0.f, 0.f, 0.f, 0.f};
            #pragma unroll
            for (int kc = 0; kc < 4; ++kc)
                rs = __builtin_amdgcn_mfma_f32_16x16x32_bf16(pf[kc], ones, rs, 0, 0, 0);
            #pragma unroll
            for (int r = 0; r < 4; ++r) l4[st][r] += rs[r];
            #pragma unroll
            for (int dt = 0; dt < 4; ++dt) {
                #pragma unroll
                for (int kc = 0; kc < 4; ++kc) {
                    int d = dt * 16 + cl;
                    int slot = d * 16 + ((kc * 4 + quad) ^ (d & 15));
                    bf16x8 vf = *(const bf16x8*)(Vt + slot * 8);
                    o_acc[st][dt] = __builtin_amdgcn_mfma_f32_16x16x32_bf16(pf[kc], vf, o_acc[st][dt], 0, 0, 0);
                }
            }
        }
    }

    // epilogue: O/l -> bf16 store
    #pragma unroll
    for (int st = 0; st < 2; ++st) {
        f32x4 linv;
        #pragma unroll
        for (int r = 0; r < 4; ++r) linv[r] = __builtin_amdgcn_rcpf(l4[st][r]);
        #pragma unroll
        for (int dt = 0; dt < 4; ++dt)
            #pragma unroll
            for (int r = 0; r < 4; ++r) {
                float val = o_acc[st][dt][r] * linv[r];
                size_t row = (size_t)n * CHUNK + s0 + st * 16 + quad * 4 + r;
                O[row * D_MODEL + h * HDIM + dt * 16 + cl] = f2bf(val);
            }
    }
}

extern "C" void kernel_launch(void* const* d_in, const int* in_sizes, int n_in,
                              void* d_out, int out_size, void* d_ws, size_t ws_size,
                              hipStream_t stream) {
    const float* hs = (const float*)d_in[0];
    const float* Wq = (const float*)d_in[1];
    const float* Wk = (const float*)d_in[2];
    const float* Wv = (const float*)d_in[3];
    const float* Wo = (const float*)d_in[4];
    float* out = (float*)d_out;

    char* ws = (char*)d_ws;
    const size_t MB = 1024 * 1024;
    short* Xbf  = (short*)(ws);              // 16 MB  [8192][1024]
    short* QKb  = (short*)(ws + 16 * MB);    // 32 MB  [8192][2048]  (Q | K)
    short* VT   = (short*)(ws + 48 * MB);    // 16 MB  [h][n][d][key]
    short* Abf  = (short*)(ws + 64 * MB);    // 16 MB  [8192][1024]
    short* Wqkv = (short*)(ws + 80 * MB);    //  6 MB  [3072][1024]
    short* Wob  = (short*)(ws + 86 * MB);    //  2 MB

    const int nHS = SEQ * D_MODEL;
    cvt_f32_bf16<<<nHS / 1024, 256, 0, stream>>>(hs, Xbf, nHS);
    cvt_w4<<<4096, 256, 0, stream>>>(Wq, Wk, Wv, Wo, Wqkv, Wob);

    gemm_qkv<<<dim3(24, 64), 256, 0, stream>>>(Xbf, Wqkv, QKb, VT);

    attn_kernel<<<dim3(16, NCHUNK, NHEADS), 256, 0, stream>>>(QKb, VT, Abf);

    gemm_out<<<dim3(8, 64), 256, 0, stream>>>(Abf, Wob, out, SEQ, D_MODEL, D_MODEL);
}

// Round 9
// 301.853 us; speedup vs baseline: 1.6271x; 1.0253x over previous
//
#include <hip/hip_runtime.h>
#include <stdint.h>

#define D_MODEL 1024
#define NHEADS 16
#define HDIM 64
#define CHUNK 2048
#define SEQ 8192
#define NCHUNK 4

typedef __attribute__((ext_vector_type(8))) short bf16x8;
typedef __attribute__((ext_vector_type(4))) float f32x4;

static __device__ __forceinline__ short f2bf(float f) {
    unsigned int u = __builtin_bit_cast(unsigned int, f);
    u = (u + 0x7FFFu + ((u >> 16) & 1u)) >> 16;
    return (short)u;
}

static __device__ __forceinline__ unsigned int pkbf(float a, float b) {
    unsigned int ua = __builtin_bit_cast(unsigned int, a) + 0x8000u;
    unsigned int ub = __builtin_bit_cast(unsigned int, b) + 0x8000u;
    return (ua >> 16) | (ub & 0xFFFF0000u);
}

static __device__ __forceinline__ void gl_lds16(const void* g, void* l) {
    __builtin_amdgcn_global_load_lds((__attribute__((address_space(1))) void*)g,
                                     (__attribute__((address_space(3))) void*)l,
                                     16, 0, 0);
}

// ---------------- fp32 -> bf16 conversion (hidden states) ----------------
__global__ void cvt_f32_bf16(const float* __restrict__ in, short* __restrict__ out, int n) {
    int i = (blockIdx.x * 256 + threadIdx.x) * 4;
    if (i >= n) return;
    float4 v = *(const float4*)(in + i);
    short4 o;
    o.x = f2bf(v.x); o.y = f2bf(v.y); o.z = f2bf(v.z); o.w = f2bf(v.w);
    *(short4*)(out + i) = o;
}

// ---------------- all four weights in one launch ----------------
__global__ void cvt_w4(const float* __restrict__ Wq, const float* __restrict__ Wk,
                       const float* __restrict__ Wv, const float* __restrict__ Wo,
                       short* __restrict__ Wqkv, short* __restrict__ Wob) {
    const int nW = D_MODEL * D_MODEL;
    int b = blockIdx.x;
    int which = b >> 10;
    const float* src = (which == 0) ? Wq : (which == 1) ? Wk : (which == 2) ? Wv : Wo;
    short* dst = (which < 3) ? (Wqkv + which * nW) : Wob;
    int i = ((b & 1023) * 256 + threadIdx.x) * 4;
    float4 v = *(const float4*)(src + i);
    short4 o;
    o.x = f2bf(v.x); o.y = f2bf(v.y); o.z = f2bf(v.z); o.w = f2bf(v.w);
    *(short4*)(dst + i) = o;
}

// ---------------- fused QKV GEMM, BK=64 ----------------
__global__ __launch_bounds__(256) void gemm_qkv(const short* __restrict__ A,
                                                const short* __restrict__ B,
                                                short* __restrict__ QK,
                                                short* __restrict__ VT) {
    __shared__ __align__(16) short As[128 * 64];
    __shared__ __align__(16) short Bs[128 * 64];
    const int tid  = threadIdx.x;
    const int lane = tid & 63;
    const int w    = tid >> 6;
    const int wr   = w >> 1, wc = w & 1;
    const int rowBase = blockIdx.y * 128;
    const int colBase = blockIdx.x * 128;
    const int quad = lane >> 4;
    const int cl   = lane & 15;
    const int K = D_MODEL;

    f32x4 acc[4][4];
    #pragma unroll
    for (int i = 0; i < 4; ++i)
        #pragma unroll
        for (int j = 0; j < 4; ++j)
            acc[i][j] = (f32x4){0.f, 0.f, 0.f, 0.f};

    int srow[4], skc[4];
    #pragma unroll
    for (int j = 0; j < 4; ++j) {
        int s = j * 256 + tid;
        srow[j] = s >> 3;
        skc[j]  = ((s & 7) ^ (srow[j] & 7)) * 8;
    }

    for (int k0 = 0; k0 < K; k0 += 64) {
        #pragma unroll
        for (int j = 0; j < 4; ++j) {
            gl_lds16(A + (size_t)(rowBase + srow[j]) * K + k0 + skc[j], &As[(j * 256 + tid) * 8]);
            gl_lds16(B + (size_t)(colBase + srow[j]) * K + k0 + skc[j], &Bs[(j * 256 + tid) * 8]);
        }
        __syncthreads();

        #pragma unroll
        for (int hf = 0; hf < 2; ++hf) {
            bf16x8 af[4], bfr[4];
            #pragma unroll
            for (int mi = 0; mi < 4; ++mi) {
                int row = wr * 64 + mi * 16 + cl;
                af[mi] = *(const bf16x8*)&As[row * 64 + (((hf * 4 + quad) ^ (cl & 7)) * 8)];
            }
            #pragma unroll
            for (int ni = 0; ni < 4; ++ni) {
                int row = wc * 64 + ni * 16 + cl;
                bfr[ni] = *(const bf16x8*)&Bs[row * 64 + (((hf * 4 + quad) ^ (cl & 7)) * 8)];
            }
            #pragma unroll
            for (int mi = 0; mi < 4; ++mi)
                #pragma unroll
                for (int ni = 0; ni < 4; ++ni)
                    acc[mi][ni] = __builtin_amdgcn_mfma_f32_16x16x32_bf16(af[mi], bfr[ni], acc[mi][ni], 0, 0, 0);
        }
        __syncthreads();
    }

    if (colBase < 2048) {
        #pragma unroll
        for (int mi = 0; mi < 4; ++mi)
            #pragma unroll
            for (int ni = 0; ni < 4; ++ni)
                #pragma unroll
                for (int r = 0; r < 4; ++r) {
                    int row = rowBase + wr * 64 + mi * 16 + quad * 4 + r;
                    int col = colBase + wc * 64 + ni * 16 + cl;
                    QK[(size_t)row * 2048 + col] = f2bf(acc[mi][ni][r]);
                }
    } else {
        #pragma unroll
        for (int mi = 0; mi < 4; ++mi) {
            int row0 = rowBase + wr * 64 + mi * 16 + quad * 4;
            int n = row0 >> 11, key = row0 & 2047;
            #pragma unroll
            for (int ni = 0; ni < 4; ++ni) {
                int c3 = colBase - 2048 + wc * 64 + ni * 16 + cl;
                int h = c3 >> 6, d = c3 & 63;
                short4 o;
                o.x = f2bf(acc[mi][ni][0]);
                o.y = f2bf(acc[mi][ni][1]);
                o.z = f2bf(acc[mi][ni][2]);
                o.w = f2bf(acc[mi][ni][3]);
                *(short4*)(VT + (size_t)((h * NCHUNK + n) * HDIM + d) * CHUNK + key) = o;
            }
        }
    }
}

// ---------------- output projection GEMM, BK=64 ----------------
__global__ __launch_bounds__(256) void gemm_out(const short* __restrict__ A,
                                                const short* __restrict__ B,
                                                float* __restrict__ Cout,
                                                int M, int N, int K) {
    __shared__ __align__(16) short As[128 * 64];
    __shared__ __align__(16) short Bs[128 * 64];
    const int tid  = threadIdx.x;
    const int lane = tid & 63;
    const int w    = tid >> 6;
    const int wr   = w >> 1, wc = w & 1;
    const int rowBase = blockIdx.y * 128;
    const int colBase = blockIdx.x * 128;
    const int quad = lane >> 4;
    const int cl   = lane & 15;

    f32x4 acc[4][4];
    #pragma unroll
    for (int i = 0; i < 4; ++i)
        #pragma unroll
        for (int j = 0; j < 4; ++j)
            acc[i][j] = (f32x4){0.f, 0.f, 0.f, 0.f};

    int srow[4], skc[4];
    #pragma unroll
    for (int j = 0; j < 4; ++j) {
        int s = j * 256 + tid;
        srow[j] = s >> 3;
        skc[j]  = ((s & 7) ^ (srow[j] & 7)) * 8;
    }

    for (int k0 = 0; k0 < K; k0 += 64) {
        #pragma unroll
        for (int j = 0; j < 4; ++j) {
            gl_lds16(A + (size_t)(rowBase + srow[j]) * K + k0 + skc[j], &As[(j * 256 + tid) * 8]);
            gl_lds16(B + (size_t)(colBase + srow[j]) * K + k0 + skc[j], &Bs[(j * 256 + tid) * 8]);
        }
        __syncthreads();

        #pragma unroll
        for (int hf = 0; hf < 2; ++hf) {
            bf16x8 af[4], bfr[4];
            #pragma unroll
            for (int mi = 0; mi < 4; ++mi) {
                int row = wr * 64 + mi * 16 + cl;
                af[mi] = *(const bf16x8*)&As[row * 64 + (((hf * 4 + quad) ^ (cl & 7)) * 8)];
            }
            #pragma unroll
            for (int ni = 0; ni < 4; ++ni) {
                int row = wc * 64 + ni * 16 + cl;
                bfr[ni] = *(const bf16x8*)&Bs[row * 64 + (((hf * 4 + quad) ^ (cl & 7)) * 8)];
            }
            #pragma unroll
            for (int mi = 0; mi < 4; ++mi)
                #pragma unroll
                for (int ni = 0; ni < 4; ++ni)
                    acc[mi][ni] = __builtin_amdgcn_mfma_f32_16x16x32_bf16(af[mi], bfr[ni], acc[mi][ni], 0, 0, 0);
        }
        __syncthreads();
    }

    #pragma unroll
    for (int mi = 0; mi < 4; ++mi)
        #pragma unroll
        for (int ni = 0; ni < 4; ++ni)
            #pragma unroll
            for (int r = 0; r < 4; ++r) {
                int row = rowBase + wr * 64 + mi * 16 + quad * 4 + r;
                int col = colBase + wc * 64 + ni * 16 + cl;
                Cout[(size_t)row * N + col] = acc[mi][ni][r];
            }
}

// ---------------- flash attention, chunk-local causal ----------------
// Dual-buffer async staging with TWO DISTINCT static LDS arrays (KVa/KVb)
// and macro-duplicated loop bodies using compile-time-constant bases, so
// alias analysis can prove ds_reads(cur) disjoint from in-flight
// global_load_lds(next) — R8's single KV[2][] object forced a defensive
// vmcnt(0) before the first fragment read, serializing stage/compute.
// No register state added across bodies (R3/R5/R6 spill lesson).

#define ATTN_STAGE(BUF, T)                                                   \
    {                                                                        \
        const int kb2_ = (T) * 128;                                          \
        _Pragma("unroll")                                                    \
        for (int j = 0; j < 4; ++j) {                                        \
            int s = j * 256 + tid;                                           \
            int row = s >> 3;                                                \
            int c = (s & 7) ^ ((row >> 3) & 7);                              \
            gl_lds16(Kg + (size_t)(kb2_ + row) * 2048 + c * 8, &BUF[s * 8]); \
        }                                                                    \
        _Pragma("unroll")                                                    \
        for (int j = 0; j < 4; ++j) {                                        \
            int s = j * 256 + tid;                                           \
            int d = s >> 4;                                                  \
            int c = (s & 15) ^ (d & 15);                                     \
            gl_lds16(VTg + (size_t)d * CHUNK + kb2_ + c * 8,                 \
                     &BUF[8192 + s * 8]);                                    \
        }                                                                    \
    }

#define ATTN_COMPUTE(BUF, T)                                                  \
    {                                                                         \
        const int kb_ = (T) * 128;                                            \
        const bool full_ = ((T) < qi);                                        \
        _Pragma("unroll")                                                     \
        for (int st = 0; st < 2; ++st) {                                      \
            const int sb = s0 + st * 16;                                      \
            f32x4 sa[8];                                                      \
            _Pragma("unroll")                                                 \
            for (int kt = 0; kt < 8; ++kt) {                                  \
                int row = 8 * cl + kt;                                        \
                bf16x8 k0 = *(const bf16x8*)(&BUF[(row * 8 + (quad ^ (cl & 7))) * 8]);       \
                bf16x8 k1 = *(const bf16x8*)(&BUF[(row * 8 + ((4 + quad) ^ (cl & 7))) * 8]); \
                sa[kt] = (f32x4){0.f, 0.f, 0.f, 0.f};                         \
                sa[kt] = __builtin_amdgcn_mfma_f32_16x16x32_bf16(qf[st][0], k0, sa[kt], 0, 0, 0); \
                sa[kt] = __builtin_amdgcn_mfma_f32_16x16x32_bf16(qf[st][1], k1, sa[kt], 0, 0, 0); \
            }                                                                 \
            if (!full_) {                                                     \
                int k8 = kb_ + 8 * cl;                                        \
                _Pragma("unroll")                                             \
                for (int r = 0; r < 4; ++r) {                                 \
                    int q = sb + quad * 4 + r;                                \
                    _Pragma("unroll")                                         \
                    for (int kt = 0; kt < 8; ++kt)                            \
                        if (k8 + kt > q) sa[kt][r] = -3.0e38f;                \
                }                                                             \
            }                                                                 \
            f32x4 mx;                                                         \
            _Pragma("unroll")                                                 \
            for (int r = 0; r < 4; ++r)                                       \
                mx[r] = fmaxf(fmaxf(fmaxf(sa[0][r], sa[1][r]), fmaxf(sa[2][r], sa[3][r])),   \
                              fmaxf(fmaxf(sa[4][r], sa[5][r]), fmaxf(sa[6][r], sa[7][r])));  \
            _Pragma("unroll")                                                 \
            for (int r = 0; r < 4; ++r) {                                     \
                float m = mx[r];                                              \
                m = fmaxf(m, __shfl_xor(m, 1));                               \
                m = fmaxf(m, __shfl_xor(m, 2));                               \
                m = fmaxf(m, __shfl_xor(m, 4));                               \
                m = fmaxf(m, __shfl_xor(m, 8));                               \
                mx[r] = m;                                                    \
            }                                                                 \
            f32x4 alpha, nm;                                                  \
            _Pragma("unroll")                                                 \
            for (int r = 0; r < 4; ++r) {                                     \
                float mnew = fmaxf(m4[st][r], mx[r]);                         \
                alpha[r] = __builtin_amdgcn_exp2f((m4[st][r] - mnew) * cs);   \
                nm[r] = mnew * cs;                                            \
                m4[st][r] = mnew;                                             \
            }                                                                 \
            _Pragma("unroll")                                                 \
            for (int r = 0; r < 4; ++r) l4[st][r] *= alpha[r];                \
            _Pragma("unroll")                                                 \
            for (int dt = 0; dt < 4; ++dt)                                    \
                _Pragma("unroll")                                             \
                for (int r = 0; r < 4; ++r) o_acc[st][dt][r] *= alpha[r];     \
            _Pragma("unroll")                                                 \
            for (int r = 0; r < 4; ++r) {                                     \
                float p0 = __builtin_amdgcn_exp2f(__builtin_fmaf(sa[0][r], cs, -nm[r])); \
                float p1 = __builtin_amdgcn_exp2f(__builtin_fmaf(sa[1][r], cs, -nm[r])); \
                float p2 = __builtin_amdgcn_exp2f(__builtin_fmaf(sa[2][r], cs, -nm[r])); \
                float p3 = __builtin_amdgcn_exp2f(__builtin_fmaf(sa[3][r], cs, -nm[r])); \
                float p4 = __builtin_amdgcn_exp2f(__builtin_fmaf(sa[4][r], cs, -nm[r])); \
                float p5 = __builtin_amdgcn_exp2f(__builtin_fmaf(sa[5][r], cs, -nm[r])); \
                float p6 = __builtin_amdgcn_exp2f(__builtin_fmaf(sa[6][r], cs, -nm[r])); \
                float p7 = __builtin_amdgcn_exp2f(__builtin_fmaf(sa[7][r], cs, -nm[r])); \
                uint4 pk;                                                     \
                pk.x = pkbf(p0, p1);                                          \
                pk.y = pkbf(p2, p3);                                          \
                pk.z = pkbf(p4, p5);                                          \
                pk.w = pkbf(p6, p7);                                          \
                int m = quad * 4 + r;                                         \
                *(uint4*)(Pw + (m * 16 + (cl ^ m)) * 8) = pk;                 \
            }                                                                 \
            bf16x8 pf[4];                                                     \
            _Pragma("unroll")                                                 \
            for (int kc = 0; kc < 4; ++kc)                                    \
                pf[kc] = *(const bf16x8*)(Pw + (cl * 16 + ((kc * 4 + quad) ^ cl)) * 8); \
            f32x4 rs = (f32x4){0.f, 0.f, 0.f, 0.f};                           \
            _Pragma("unroll")                                                 \
            for (int kc = 0; kc < 4; ++kc)                                    \
                rs = __builtin_amdgcn_mfma_f32_16x16x32_bf16(pf[kc], ones, rs, 0, 0, 0); \
            _Pragma("unroll")                                                 \
            for (int r = 0; r < 4; ++r) l4[st][r] += rs[r];                   \
            _Pragma("unroll")                                                 \
            for (int dt = 0; dt < 4; ++dt) {                                  \
                _Pragma("unroll")                                             \
                for (int kc = 0; kc < 4; ++kc) {                              \
                    int d = dt * 16 + cl;                                     \
                    int slot = d * 16 + ((kc * 4 + quad) ^ (d & 15));         \
                    bf16x8 vf = *(const bf16x8*)(&BUF[8192 + slot * 8]);      \
                    o_acc[st][dt] = __builtin_amdgcn_mfma_f32_16x16x32_bf16(pf[kc], vf, o_acc[st][dt], 0, 0, 0); \
                }                                                             \
            }                                                                 \
        }                                                                     \
    }

__global__ __launch_bounds__(256, 2) void attn_kernel(const short* __restrict__ QK,
                                                      const short* __restrict__ VT,
                                                      short* __restrict__ O) {
    __shared__ __align__(16) short KVa[16384];  // K: 0..8191, V: 8192..16383
    __shared__ __align__(16) short KVb[16384];
    __shared__ __align__(16) short Pt[8192];
    const int tid  = threadIdx.x;
    const int lane = tid & 63;
    const int w    = tid >> 6;
    const int quad = lane >> 4;
    const int cl   = lane & 15;
    const int h = blockIdx.z;
    const int n = blockIdx.y;
    const int qi  = (blockIdx.x + blockIdx.y + blockIdx.z) & 15;  // balance swizzle
    const int qb0 = qi * 128;
    const int s0  = qb0 + w * 32;

    const short* Qg  = QK + (size_t)n * CHUNK * 2048 + h * HDIM;
    const short* Kg  = QK + (size_t)n * CHUNK * 2048 + 1024 + h * HDIM;
    const short* VTg = VT + (size_t)(h * NCHUNK + n) * HDIM * CHUNK;
    short* Pw = Pt + w * 2048;

    bf16x8 qf[2][2];
    #pragma unroll
    for (int st = 0; st < 2; ++st)
        #pragma unroll
        for (int hf = 0; hf < 2; ++hf)
            qf[st][hf] = *(const bf16x8*)(Qg + (size_t)(s0 + st * 16 + cl) * 2048 + hf * 32 + quad * 8);

    bf16x8 ones;
    #pragma unroll
    for (int i = 0; i < 8; ++i) ones[i] = (short)0x3F80;

    f32x4 m4[2], l4[2], o_acc[2][4];
    #pragma unroll
    for (int st = 0; st < 2; ++st) {
        m4[st] = (f32x4){-3.0e38f, -3.0e38f, -3.0e38f, -3.0e38f};
        l4[st] = (f32x4){0.f, 0.f, 0.f, 0.f};
        #pragma unroll
        for (int dt = 0; dt < 4; ++dt) o_acc[st][dt] = (f32x4){0.f, 0.f, 0.f, 0.f};
    }

    const float cs = 0.18033688011f;  // log2(e)/sqrt(64)
    const int ntiles = qi + 1;

    ATTN_STAGE(KVa, 0);
    int t = 0;
    for (;;) {
        __syncthreads();  // KVa staged (vmcnt drained at barrier); readers of KVb done
        if (t + 1 < ntiles) ATTN_STAGE(KVb, t + 1);  // async into the OTHER array
        ATTN_COMPUTE(KVa, t);                        // provably disjoint from KVb
        if (++t >= ntiles) break;
        __syncthreads();  // KVb staged; readers of KVa done
        if (t + 1 < ntiles) ATTN_STAGE(KVa, t + 1);
        ATTN_COMPUTE(KVb, t);
        if (++t >= ntiles) break;
    }

    // epilogue: O/l -> bf16 store
    #pragma unroll
    for (int st = 0; st < 2; ++st) {
        f32x4 linv;
        #pragma unroll
        for (int r = 0; r < 4; ++r) linv[r] = __builtin_amdgcn_rcpf(l4[st][r]);
        #pragma unroll
        for (int dt = 0; dt < 4; ++dt)
            #pragma unroll
            for (int r = 0; r < 4; ++r) {
                float val = o_acc[st][dt][r] * linv[r];
                size_t row = (size_t)n * CHUNK + s0 + st * 16 + quad * 4 + r;
                O[row * D_MODEL + h * HDIM + dt * 16 + cl] = f2bf(val);
            }
    }
}

extern "C" void kernel_launch(void* const* d_in, const int* in_sizes, int n_in,
                              void* d_out, int out_size, void* d_ws, size_t ws_size,
                              hipStream_t stream) {
    const float* hs = (const float*)d_in[0];
    const float* Wq = (const float*)d_in[1];
    const float* Wk = (const float*)d_in[2];
    const float* Wv = (const float*)d_in[3];
    const float* Wo = (const float*)d_in[4];
    float* out = (float*)d_out;

    char* ws = (char*)d_ws;
    const size_t MB = 1024 * 1024;
    short* Xbf  = (short*)(ws);              // 16 MB  [8192][1024]
    short* QKb  = (short*)(ws + 16 * MB);    // 32 MB  [8192][2048]  (Q | K)
    short* VT   = (short*)(ws + 48 * MB);    // 16 MB  [h][n][d][key]
    short* Abf  = (short*)(ws + 64 * MB);    // 16 MB  [8192][1024]
    short* Wqkv = (short*)(ws + 80 * MB);    //  6 MB  [3072][1024]
    short* Wob  = (short*)(ws + 86 * MB);    //  2 MB

    const int nHS = SEQ * D_MODEL;
    cvt_f32_bf16<<<nHS / 1024, 256, 0, stream>>>(hs, Xbf, nHS);
    cvt_w4<<<4096, 256, 0, stream>>>(Wq, Wk, Wv, Wo, Wqkv, Wob);

    gemm_qkv<<<dim3(24, 64), 256, 0, stream>>>(Xbf, Wqkv, QKb, VT);

    attn_kernel<<<dim3(16, NCHUNK, NHEADS), 256, 0, stream>>>(QKb, VT, Abf);

    gemm_out<<<dim3(8, 64), 256, 0, stream>>>(Abf, Wob, out, SEQ, D_MODEL, D_MODEL);
}

// Round 10
// 278.796 us; speedup vs baseline: 1.7616x; 1.0827x over previous
//
#include <hip/hip_runtime.h>
#include <stdint.h>

#define D_MODEL 1024
#define NHEADS 16
#define HDIM 64
#define CHUNK 2048
#define SEQ 8192
#define NCHUNK 4

typedef __attribute__((ext_vector_type(8))) short bf16x8;
typedef __attribute__((ext_vector_type(4))) float f32x4;

static __device__ __forceinline__ short f2bf(float f) {
    unsigned int u = __builtin_bit_cast(unsigned int, f);
    u = (u + 0x7FFFu + ((u >> 16) & 1u)) >> 16;
    return (short)u;
}

static __device__ __forceinline__ unsigned int pkbf(float a, float b) {
    unsigned int ua = __builtin_bit_cast(unsigned int, a) + 0x8000u;
    unsigned int ub = __builtin_bit_cast(unsigned int, b) + 0x8000u;
    return (ua >> 16) | (ub & 0xFFFF0000u);
}

static __device__ __forceinline__ void gl_lds16(const void* g, void* l) {
    __builtin_amdgcn_global_load_lds((__attribute__((address_space(1))) void*)g,
                                     (__attribute__((address_space(3))) void*)l,
                                     16, 0, 0);
}

// ---------------- fp32 -> bf16 conversion (hidden states) ----------------
__global__ void cvt_f32_bf16(const float* __restrict__ in, short* __restrict__ out, int n) {
    int i = (blockIdx.x * 256 + threadIdx.x) * 4;
    if (i >= n) return;
    float4 v = *(const float4*)(in + i);
    short4 o;
    o.x = f2bf(v.x); o.y = f2bf(v.y); o.z = f2bf(v.z); o.w = f2bf(v.w);
    *(short4*)(out + i) = o;
}

// ---------------- all four weights in one launch ----------------
__global__ void cvt_w4(const float* __restrict__ Wq, const float* __restrict__ Wk,
                       const float* __restrict__ Wv, const float* __restrict__ Wo,
                       short* __restrict__ Wqkv, short* __restrict__ Wob) {
    const int nW = D_MODEL * D_MODEL;
    int b = blockIdx.x;
    int which = b >> 10;
    const float* src = (which == 0) ? Wq : (which == 1) ? Wk : (which == 2) ? Wv : Wo;
    short* dst = (which < 3) ? (Wqkv + which * nW) : Wob;
    int i = ((b & 1023) * 256 + threadIdx.x) * 4;
    float4 v = *(const float4*)(src + i);
    short4 o;
    o.x = f2bf(v.x); o.y = f2bf(v.y); o.z = f2bf(v.z); o.w = f2bf(v.w);
    *(short4*)(dst + i) = o;
}

// ---------------- fused QKV GEMM, BK=64 ----------------
__global__ __launch_bounds__(256) void gemm_qkv(const short* __restrict__ A,
                                                const short* __restrict__ B,
                                                short* __restrict__ QK,
                                                short* __restrict__ VT) {
    __shared__ __align__(16) short As[128 * 64];
    __shared__ __align__(16) short Bs[128 * 64];
    const int tid  = threadIdx.x;
    const int lane = tid & 63;
    const int w    = tid >> 6;
    const int wr   = w >> 1, wc = w & 1;
    const int rowBase = blockIdx.y * 128;
    const int colBase = blockIdx.x * 128;
    const int quad = lane >> 4;
    const int cl   = lane & 15;
    const int K = D_MODEL;

    f32x4 acc[4][4];
    #pragma unroll
    for (int i = 0; i < 4; ++i)
        #pragma unroll
        for (int j = 0; j < 4; ++j)
            acc[i][j] = (f32x4){0.f, 0.f, 0.f, 0.f};

    int srow[4], skc[4];
    #pragma unroll
    for (int j = 0; j < 4; ++j) {
        int s = j * 256 + tid;
        srow[j] = s >> 3;
        skc[j]  = ((s & 7) ^ (srow[j] & 7)) * 8;
    }

    for (int k0 = 0; k0 < K; k0 += 64) {
        #pragma unroll
        for (int j = 0; j < 4; ++j) {
            gl_lds16(A + (size_t)(rowBase + srow[j]) * K + k0 + skc[j], &As[(j * 256 + tid) * 8]);
            gl_lds16(B + (size_t)(colBase + srow[j]) * K + k0 + skc[j], &Bs[(j * 256 + tid) * 8]);
        }
        __syncthreads();

        #pragma unroll
        for (int hf = 0; hf < 2; ++hf) {
            bf16x8 af[4], bfr[4];
            #pragma unroll
            for (int mi = 0; mi < 4; ++mi) {
                int row = wr * 64 + mi * 16 + cl;
                af[mi] = *(const bf16x8*)&As[row * 64 + (((hf * 4 + quad) ^ (row & 7)) * 8)];
            }
            #pragma unroll
            for (int ni = 0; ni < 4; ++ni) {
                int row = wc * 64 + ni * 16 + cl;
                bfr[ni] = *(const bf16x8*)&Bs[row * 64 + (((hf * 4 + quad) ^ (row & 7)) * 8)];
            }
            #pragma unroll
            for (int mi = 0; mi < 4; ++mi)
                #pragma unroll
                for (int ni = 0; ni < 4; ++ni)
                    acc[mi][ni] = __builtin_amdgcn_mfma_f32_16x16x32_bf16(af[mi], bfr[ni], acc[mi][ni], 0, 0, 0);
        }
        __syncthreads();
    }

    if (colBase < 2048) {
        #pragma unroll
        for (int mi = 0; mi < 4; ++mi)
            #pragma unroll
            for (int ni = 0; ni < 4; ++ni)
                #pragma unroll
                for (int r = 0; r < 4; ++r) {
                    int row = rowBase + wr * 64 + mi * 16 + quad * 4 + r;
                    int col = colBase + wc * 64 + ni * 16 + cl;
                    QK[(size_t)row * 2048 + col] = f2bf(acc[mi][ni][r]);
                }
    } else {
        #pragma unroll
        for (int mi = 0; mi < 4; ++mi) {
            int row0 = rowBase + wr * 64 + mi * 16 + quad * 4;
            int n = row0 >> 11, key = row0 & 2047;
            #pragma unroll
            for (int ni = 0; ni < 4; ++ni) {
                int c3 = colBase - 2048 + wc * 64 + ni * 16 + cl;
                int h = c3 >> 6, d = c3 & 63;
                short4 o;
                o.x = f2bf(acc[mi][ni][0]);
                o.y = f2bf(acc[mi][ni][1]);
                o.z = f2bf(acc[mi][ni][2]);
                o.w = f2bf(acc[mi][ni][3]);
                *(short4*)(VT + (size_t)((h * NCHUNK + n) * HDIM + d) * CHUNK + key) = o;
            }
        }
    }
}

// ---------------- output projection GEMM, BK=64 ----------------
__global__ __launch_bounds__(256) void gemm_out(const short* __restrict__ A,
                                                const short* __restrict__ B,
                                                float* __restrict__ Cout,
                                                int M, int N, int K) {
    __shared__ __align__(16) short As[128 * 64];
    __shared__ __align__(16) short Bs[128 * 64];
    const int tid  = threadIdx.x;
    const int lane = tid & 63;
    const int w    = tid >> 6;
    const int wr   = w >> 1, wc = w & 1;
    const int rowBase = blockIdx.y * 128;
    const int colBase = blockIdx.x * 128;
    const int quad = lane >> 4;
    const int cl   = lane & 15;

    f32x4 acc[4][4];
    #pragma unroll
    for (int i = 0; i < 4; ++i)
        #pragma unroll
        for (int j = 0; j < 4; ++j)
            acc[i][j] = (f32x4){0.f, 0.f, 0.f, 0.f};

    int srow[4], skc[4];
    #pragma unroll
    for (int j = 0; j < 4; ++j) {
        int s = j * 256 + tid;
        srow[j] = s >> 3;
        skc[j]  = ((s & 7) ^ (srow[j] & 7)) * 8;
    }

    for (int k0 = 0; k0 < K; k0 += 64) {
        #pragma unroll
        for (int j = 0; j < 4; ++j) {
            gl_lds16(A + (size_t)(rowBase + srow[j]) * K + k0 + skc[j], &As[(j * 256 + tid) * 8]);
            gl_lds16(B + (size_t)(colBase + srow[j]) * K + k0 + skc[j], &Bs[(j * 256 + tid) * 8]);
        }
        __syncthreads();

        #pragma unroll
        for (int hf = 0; hf < 2; ++hf) {
            bf16x8 af[4], bfr[4];
            #pragma unroll
            for (int mi = 0; mi < 4; ++mi) {
                int row = wr * 64 + mi * 16 + cl;
                af[mi] = *(const bf16x8*)&As[row * 64 + (((hf * 4 + quad) ^ (row & 7)) * 8)];
            }
            #pragma unroll
            for (int ni = 0; ni < 4; ++ni) {
                int row = wc * 64 + ni * 16 + cl;
                bfr[ni] = *(const bf16x8*)&Bs[row * 64 + (((hf * 4 + quad) ^ (row & 7)) * 8)];
            }
            #pragma unroll
            for (int mi = 0; mi < 4; ++mi)
                #pragma unroll
                for (int ni = 0; ni < 4; ++ni)
                    acc[mi][ni] = __builtin_amdgcn_mfma_f32_16x16x32_bf16(af[mi], bfr[ni], acc[mi][ni], 0, 0, 0);
        }
        __syncthreads();
    }

    #pragma unroll
    for (int mi = 0; mi < 4; ++mi)
        #pragma unroll
        for (int ni = 0; ni < 4; ++ni)
            #pragma unroll
            for (int r = 0; r < 4; ++r) {
                int row = rowBase + wr * 64 + mi * 16 + quad * 4 + r;
                int col = colBase + wc * 64 + ni * 16 + cl;
                Cout[(size_t)row * N + col] = acc[mi][ni][r];
            }
}

// ---------------- flash attention, chunk-local causal (TRANSPOSED) ----------------
// Computes S^T = K Q^T and O^T = V^T P^T so each lane owns ONE q-row
// (q = sb+cl): softmax reductions = 2 shuffles (xor 16,32), scalar m/l/alpha,
// and P^T never leaves registers (exp2 outputs are already in B-operand
// layout under key permutation kappa(quad,j) = (2g+(j>>2))*16+quad*4+(j&3);
// V A-fragments = two b64 reads matching that order). Pt LDS eliminated.
// Dual distinct LDS arrays (KVa/KVb) + macro bodies kept from R9.
// K staging swizzle uses (row&7) so kf-read bank granule = quad^(cl&7): uniform.

#define ATTN_STAGE(BUF, T)                                                   \
    {                                                                        \
        const int kb2_ = (T) * 128;                                          \
        _Pragma("unroll")                                                    \
        for (int j = 0; j < 4; ++j) {                                        \
            int s = j * 256 + tid;                                           \
            int row = s >> 3;                                                \
            int c = (s & 7) ^ (row & 7);                                     \
            gl_lds16(Kg + (size_t)(kb2_ + row) * 2048 + c * 8, &BUF[s * 8]); \
        }                                                                    \
        _Pragma("unroll")                                                    \
        for (int j = 0; j < 4; ++j) {                                        \
            int s = j * 256 + tid;                                           \
            int d = s >> 4;                                                  \
            int c = (s & 15) ^ (d & 15);                                     \
            gl_lds16(VTg + (size_t)d * CHUNK + kb2_ + c * 8,                 \
                     &BUF[8192 + s * 8]);                                    \
        }                                                                    \
    }

#define ATTN_COMPUTE(BUF, T)                                                  \
    {                                                                         \
        const int kb_ = (T) * 128;                                            \
        const bool last_ = ((T) == qi);                                       \
        _Pragma("unroll")                                                     \
        for (int st = 0; st < 2; ++st) {                                      \
            const int sb = s0 + st * 16;                                      \
            const int qrow = sb + cl;                                         \
            f32x4 sa[8];                                                      \
            _Pragma("unroll")                                                 \
            for (int kt = 0; kt < 8; ++kt) {                                  \
                int key16 = kt * 16 + cl;                                     \
                bf16x8 k0 = *(const bf16x8*)(&BUF[(key16 * 8 + (quad ^ (cl & 7))) * 8]);       \
                bf16x8 k1 = *(const bf16x8*)(&BUF[(key16 * 8 + ((4 + quad) ^ (cl & 7))) * 8]); \
                sa[kt] = __builtin_amdgcn_mfma_f32_16x16x32_bf16(k0, qf[st][0],                \
                             (f32x4){0.f, 0.f, 0.f, 0.f}, 0, 0, 0);           \
                sa[kt] = __builtin_amdgcn_mfma_f32_16x16x32_bf16(k1, qf[st][1], sa[kt], 0, 0, 0); \
            }                                                                 \
            if (last_) {                                                      \
                _Pragma("unroll")                                             \
                for (int kt = 0; kt < 8; ++kt) {                              \
                    int kbase = kb_ + kt * 16 + quad * 4;                     \
                    _Pragma("unroll")                                         \
                    for (int r = 0; r < 4; ++r)                               \
                        if (kbase + r > qrow) sa[kt][r] = -3.0e38f;           \
                }                                                             \
            }                                                                 \
            float mx = fmaxf(fmaxf(sa[0][0], sa[0][1]), fmaxf(sa[0][2], sa[0][3])); \
            _Pragma("unroll")                                                 \
            for (int kt = 1; kt < 8; ++kt)                                    \
                mx = fmaxf(mx, fmaxf(fmaxf(sa[kt][0], sa[kt][1]),             \
                                     fmaxf(sa[kt][2], sa[kt][3])));           \
            mx = fmaxf(mx, __shfl_xor(mx, 16));                               \
            mx = fmaxf(mx, __shfl_xor(mx, 32));                               \
            float mnew = fmaxf(m2[st], mx);                                   \
            float alpha = __builtin_amdgcn_exp2f((m2[st] - mnew) * cs);       \
            float nm = mnew * cs;                                             \
            m2[st] = mnew;                                                    \
            l2[st] *= alpha;                                                  \
            _Pragma("unroll")                                                 \
            for (int dt = 0; dt < 4; ++dt)                                    \
                _Pragma("unroll")                                             \
                for (int r = 0; r < 4; ++r) o_acc[st][dt][r] *= alpha;        \
            _Pragma("unroll")                                                 \
            for (int kt = 0; kt < 8; ++kt)                                    \
                _Pragma("unroll")                                             \
                for (int r = 0; r < 4; ++r)                                   \
                    sa[kt][r] = __builtin_amdgcn_exp2f(__builtin_fmaf(sa[kt][r], cs, -nm)); \
            bf16x8 pfr[4];                                                    \
            _Pragma("unroll")                                                 \
            for (int g = 0; g < 4; ++g) {                                     \
                uint4 pk;                                                     \
                pk.x = pkbf(sa[2 * g][0], sa[2 * g][1]);                      \
                pk.y = pkbf(sa[2 * g][2], sa[2 * g][3]);                      \
                pk.z = pkbf(sa[2 * g + 1][0], sa[2 * g + 1][1]);              \
                pk.w = pkbf(sa[2 * g + 1][2], sa[2 * g + 1][3]);              \
                pfr[g] = __builtin_bit_cast(bf16x8, pk);                      \
            }                                                                 \
            f32x4 rs = (f32x4){0.f, 0.f, 0.f, 0.f};                           \
            _Pragma("unroll")                                                 \
            for (int g = 0; g < 4; ++g)                                       \
                rs = __builtin_amdgcn_mfma_f32_16x16x32_bf16(ones, pfr[g], rs, 0, 0, 0); \
            l2[st] += rs[0];                                                  \
            _Pragma("unroll")                                                 \
            for (int dt = 0; dt < 4; ++dt) {                                  \
                _Pragma("unroll")                                             \
                for (int g = 0; g < 4; ++g) {                                 \
                    int c0 = 4 * g + (quad >> 1);                             \
                    int base = (dt * 16 + cl) * 16;                           \
                    int q4 = (quad & 1) * 4;                                  \
                    short4 va = *(const short4*)(&BUF[8192 + (base + (c0 ^ cl)) * 8 + q4]);       \
                    short4 vb = *(const short4*)(&BUF[8192 + (base + ((c0 + 2) ^ cl)) * 8 + q4]); \
                    bf16x8 vf = {va.x, va.y, va.z, va.w, vb.x, vb.y, vb.z, vb.w};                 \
                    o_acc[st][dt] = __builtin_amdgcn_mfma_f32_16x16x32_bf16(vf, pfr[g], o_acc[st][dt], 0, 0, 0); \
                }                                                             \
            }                                                                 \
        }                                                                     \
    }

__global__ __launch_bounds__(256, 2) void attn_kernel(const short* __restrict__ QK,
                                                      const short* __restrict__ VT,
                                                      short* __restrict__ O) {
    __shared__ __align__(16) short KVa[16384];  // K: 0..8191, V: 8192..16383
    __shared__ __align__(16) short KVb[16384];
    const int tid  = threadIdx.x;
    const int lane = tid & 63;
    const int w    = tid >> 6;
    const int quad = lane >> 4;
    const int cl   = lane & 15;
    const int h = blockIdx.z;
    const int n = blockIdx.y;
    const int qi  = (blockIdx.x + blockIdx.y + blockIdx.z) & 15;  // balance swizzle
    const int qb0 = qi * 128;
    const int s0  = qb0 + w * 32;

    const short* Qg  = QK + (size_t)n * CHUNK * 2048 + h * HDIM;
    const short* Kg  = QK + (size_t)n * CHUNK * 2048 + 1024 + h * HDIM;
    const short* VTg = VT + (size_t)(h * NCHUNK + n) * HDIM * CHUNK;

    bf16x8 qf[2][2];
    #pragma unroll
    for (int st = 0; st < 2; ++st)
        #pragma unroll
        for (int hf = 0; hf < 2; ++hf)
            qf[st][hf] = *(const bf16x8*)(Qg + (size_t)(s0 + st * 16 + cl) * 2048 + hf * 32 + quad * 8);

    bf16x8 ones;
    #pragma unroll
    for (int i = 0; i < 8; ++i) ones[i] = (short)0x3F80;

    float m2[2], l2[2];
    f32x4 o_acc[2][4];
    #pragma unroll
    for (int st = 0; st < 2; ++st) {
        m2[st] = -3.0e38f;
        l2[st] = 0.f;
        #pragma unroll
        for (int dt = 0; dt < 4; ++dt) o_acc[st][dt] = (f32x4){0.f, 0.f, 0.f, 0.f};
    }

    const float cs = 0.18033688011f;  // log2(e)/sqrt(64)
    const int ntiles = qi + 1;

    ATTN_STAGE(KVa, 0);
    int t = 0;
    for (;;) {
        __syncthreads();  // KVa staged; readers of KVb done
        if (t + 1 < ntiles) ATTN_STAGE(KVb, t + 1);
        ATTN_COMPUTE(KVa, t);
        if (++t >= ntiles) break;
        __syncthreads();  // KVb staged; readers of KVa done
        if (t + 1 < ntiles) ATTN_STAGE(KVa, t + 1);
        ATTN_COMPUTE(KVb, t);
        if (++t >= ntiles) break;
    }

    // epilogue: O^T regs -> O[q][d], lane owns q = sb+cl, d = dt*16+quad*4+r
    #pragma unroll
    for (int st = 0; st < 2; ++st) {
        float linv = __builtin_amdgcn_rcpf(l2[st]);
        size_t rowoff = ((size_t)n * CHUNK + s0 + st * 16 + cl) * D_MODEL + h * HDIM;
        #pragma unroll
        for (int dt = 0; dt < 4; ++dt) {
            short4 o;
            o.x = f2bf(o_acc[st][dt][0] * linv);
            o.y = f2bf(o_acc[st][dt][1] * linv);
            o.z = f2bf(o_acc[st][dt][2] * linv);
            o.w = f2bf(o_acc[st][dt][3] * linv);
            *(short4*)(O + rowoff + dt * 16 + quad * 4) = o;
        }
    }
}

extern "C" void kernel_launch(void* const* d_in, const int* in_sizes, int n_in,
                              void* d_out, int out_size, void* d_ws, size_t ws_size,
                              hipStream_t stream) {
    const float* hs = (const float*)d_in[0];
    const float* Wq = (const float*)d_in[1];
    const float* Wk = (const float*)d_in[2];
    const float* Wv = (const float*)d_in[3];
    const float* Wo = (const float*)d_in[4];
    float* out = (float*)d_out;

    char* ws = (char*)d_ws;
    const size_t MB = 1024 * 1024;
    short* Xbf  = (short*)(ws);              // 16 MB  [8192][1024]
    short* QKb  = (short*)(ws + 16 * MB);    // 32 MB  [8192][2048]  (Q | K)
    short* VT   = (short*)(ws + 48 * MB);    // 16 MB  [h][n][d][key]
    short* Abf  = (short*)(ws + 64 * MB);    // 16 MB  [8192][1024]
    short* Wqkv = (short*)(ws + 80 * MB);    //  6 MB  [3072][1024]
    short* Wob  = (short*)(ws + 86 * MB);    //  2 MB

    const int nHS = SEQ * D_MODEL;
    cvt_f32_bf16<<<nHS / 1024, 256, 0, stream>>>(hs, Xbf, nHS);
    cvt_w4<<<4096, 256, 0, stream>>>(Wq, Wk, Wv, Wo, Wqkv, Wob);

    gemm_qkv<<<dim3(24, 64), 256, 0, stream>>>(Xbf, Wqkv, QKb, VT);

    attn_kernel<<<dim3(16, NCHUNK, NHEADS), 256, 0, stream>>>(QKb, VT, Abf);

    gemm_out<<<dim3(8, 64), 256, 0, stream>>>(Abf, Wob, out, SEQ, D_MODEL, D_MODEL);
}

// Round 11
// 251.039 us; speedup vs baseline: 1.9564x; 1.1106x over previous
//
#include <hip/hip_runtime.h>
#include <stdint.h>

#define D_MODEL 1024
#define NHEADS 16
#define HDIM 64
#define CHUNK 2048
#define SEQ 8192
#define NCHUNK 4

typedef __attribute__((ext_vector_type(8))) short bf16x8;
typedef __attribute__((ext_vector_type(4))) float f32x4;

static __device__ __forceinline__ short f2bf(float f) {
    unsigned int u = __builtin_bit_cast(unsigned int, f);
    u = (u + 0x7FFFu + ((u >> 16) & 1u)) >> 16;
    return (short)u;
}

static __device__ __forceinline__ unsigned int pkbf(float a, float b) {
    unsigned int ua = __builtin_bit_cast(unsigned int, a) + 0x8000u;
    unsigned int ub = __builtin_bit_cast(unsigned int, b) + 0x8000u;
    return (ua >> 16) | (ub & 0xFFFF0000u);
}

static __device__ __forceinline__ void gl_lds16(const void* g, void* l) {
    __builtin_amdgcn_global_load_lds((__attribute__((address_space(1))) void*)g,
                                     (__attribute__((address_space(3))) void*)l,
                                     16, 0, 0);
}

// ---------------- fp32 -> bf16 conversion (hidden states) ----------------
__global__ void cvt_f32_bf16(const float* __restrict__ in, short* __restrict__ out, int n) {
    int i = (blockIdx.x * 256 + threadIdx.x) * 4;
    if (i >= n) return;
    float4 v = *(const float4*)(in + i);
    short4 o;
    o.x = f2bf(v.x); o.y = f2bf(v.y); o.z = f2bf(v.z); o.w = f2bf(v.w);
    *(short4*)(out + i) = o;
}

// ---------------- all four weights in one launch ----------------
__global__ void cvt_w4(const float* __restrict__ Wq, const float* __restrict__ Wk,
                       const float* __restrict__ Wv, const float* __restrict__ Wo,
                       short* __restrict__ Wqkv, short* __restrict__ Wob) {
    const int nW = D_MODEL * D_MODEL;
    int b = blockIdx.x;
    int which = b >> 10;
    const float* src = (which == 0) ? Wq : (which == 1) ? Wk : (which == 2) ? Wv : Wo;
    short* dst = (which < 3) ? (Wqkv + which * nW) : Wob;
    int i = ((b & 1023) * 256 + threadIdx.x) * 4;
    float4 v = *(const float4*)(src + i);
    short4 o;
    o.x = f2bf(v.x); o.y = f2bf(v.y); o.z = f2bf(v.z); o.w = f2bf(v.w);
    *(short4*)(dst + i) = o;
}

// ---------------- GEMM macros: dual-buffer, distinct LDS arrays ----------------
// R9/R10 lesson: distinct static __shared__ arrays + macro bodies with
// compile-time bases let alias analysis skip the defensive vmcnt(0) before
// ds_reads of the CURRENT buffer while gl_lds writes the OTHER — true
// stage/compute overlap, one barrier per K-iter. (Single-object dbuf was
// neutral: m99/m100 and R8.)

#define GEMM_STAGE(ABUF, BBUF, K0)                                            \
    {                                                                         \
        _Pragma("unroll")                                                     \
        for (int j = 0; j < 4; ++j) {                                         \
            gl_lds16(A + (size_t)(rowBase + srow[j]) * K + (K0) + skc[j],     \
                     &ABUF[(j * 256 + tid) * 8]);                             \
            gl_lds16(B + (size_t)(colBase + srow[j]) * K + (K0) + skc[j],     \
                     &BBUF[(j * 256 + tid) * 8]);                             \
        }                                                                     \
    }

#define GEMM_COMPUTE(ABUF, BBUF)                                              \
    {                                                                         \
        _Pragma("unroll")                                                     \
        for (int hf = 0; hf < 2; ++hf) {                                      \
            bf16x8 af[4], bfr[4];                                             \
            _Pragma("unroll")                                                 \
            for (int mi = 0; mi < 4; ++mi) {                                  \
                int row = wr * 64 + mi * 16 + cl;                             \
                af[mi] = *(const bf16x8*)&ABUF[row * 64 + (((hf * 4 + quad) ^ (row & 7)) * 8)]; \
            }                                                                 \
            _Pragma("unroll")                                                 \
            for (int ni = 0; ni < 4; ++ni) {                                  \
                int row = wc * 64 + ni * 16 + cl;                             \
                bfr[ni] = *(const bf16x8*)&BBUF[row * 64 + (((hf * 4 + quad) ^ (row & 7)) * 8)]; \
            }                                                                 \
            _Pragma("unroll")                                                 \
            for (int mi = 0; mi < 4; ++mi)                                    \
                _Pragma("unroll")                                             \
                for (int ni = 0; ni < 4; ++ni)                                \
                    acc[mi][ni] = __builtin_amdgcn_mfma_f32_16x16x32_bf16(af[mi], bfr[ni], acc[mi][ni], 0, 0, 0); \
        }                                                                     \
    }

#define GEMM_PRE()                                                            \
    const int tid  = threadIdx.x;                                             \
    const int lane = tid & 63;                                                \
    const int w    = tid >> 6;                                                \
    const int wr   = w >> 1, wc = w & 1;                                      \
    const int rowBase = blockIdx.y * 128;                                     \
    const int colBase = blockIdx.x * 128;                                     \
    const int quad = lane >> 4;                                               \
    const int cl   = lane & 15;                                               \
    f32x4 acc[4][4];                                                          \
    _Pragma("unroll")                                                         \
    for (int i = 0; i < 4; ++i)                                               \
        _Pragma("unroll")                                                     \
        for (int j = 0; j < 4; ++j)                                           \
            acc[i][j] = (f32x4){0.f, 0.f, 0.f, 0.f};                          \
    int srow[4], skc[4];                                                      \
    _Pragma("unroll")                                                         \
    for (int j = 0; j < 4; ++j) {                                             \
        int s = j * 256 + tid;                                                \
        srow[j] = s >> 3;                                                     \
        skc[j]  = ((s & 7) ^ (srow[j] & 7)) * 8;                              \
    }                                                                         \
    GEMM_STAGE(Asa, Bsa, 0);                                                  \
    for (int k0 = 0; k0 < K; k0 += 128) {                                     \
        __syncthreads();                                                      \
        if (k0 + 64 < K) GEMM_STAGE(Asb, Bsb, k0 + 64);                       \
        GEMM_COMPUTE(Asa, Bsa);                                               \
        __syncthreads();                                                      \
        if (k0 + 128 < K) GEMM_STAGE(Asa, Bsa, k0 + 128);                     \
        GEMM_COMPUTE(Asb, Bsb);                                               \
    }

// ---------------- fused QKV GEMM ----------------
// cols < 2048 -> QK[row][col] (stride 2048); cols >= 2048 -> V transposed
// into VT[((h*4+n)*64+d)*2048 + key].
__global__ __launch_bounds__(256) void gemm_qkv(const short* __restrict__ A,
                                                const short* __restrict__ B,
                                                short* __restrict__ QK,
                                                short* __restrict__ VT) {
    __shared__ __align__(16) short Asa[128 * 64];
    __shared__ __align__(16) short Asb[128 * 64];
    __shared__ __align__(16) short Bsa[128 * 64];
    __shared__ __align__(16) short Bsb[128 * 64];
    const int K = D_MODEL;
    GEMM_PRE();

    if (colBase < 2048) {
        #pragma unroll
        for (int mi = 0; mi < 4; ++mi)
            #pragma unroll
            for (int ni = 0; ni < 4; ++ni)
                #pragma unroll
                for (int r = 0; r < 4; ++r) {
                    int row = rowBase + wr * 64 + mi * 16 + quad * 4 + r;
                    int col = colBase + wc * 64 + ni * 16 + cl;
                    QK[(size_t)row * 2048 + col] = f2bf(acc[mi][ni][r]);
                }
    } else {
        #pragma unroll
        for (int mi = 0; mi < 4; ++mi) {
            int row0 = rowBase + wr * 64 + mi * 16 + quad * 4;
            int n = row0 >> 11, key = row0 & 2047;
            #pragma unroll
            for (int ni = 0; ni < 4; ++ni) {
                int c3 = colBase - 2048 + wc * 64 + ni * 16 + cl;
                int h = c3 >> 6, d = c3 & 63;
                short4 o;
                o.x = f2bf(acc[mi][ni][0]);
                o.y = f2bf(acc[mi][ni][1]);
                o.z = f2bf(acc[mi][ni][2]);
                o.w = f2bf(acc[mi][ni][3]);
                *(short4*)(VT + (size_t)((h * NCHUNK + n) * HDIM + d) * CHUNK + key) = o;
            }
        }
    }
}

// ---------------- output projection GEMM ----------------
__global__ __launch_bounds__(256) void gemm_out(const short* __restrict__ A,
                                                const short* __restrict__ B,
                                                float* __restrict__ Cout,
                                                int M, int N, int K) {
    __shared__ __align__(16) short Asa[128 * 64];
    __shared__ __align__(16) short Asb[128 * 64];
    __shared__ __align__(16) short Bsa[128 * 64];
    __shared__ __align__(16) short Bsb[128 * 64];
    GEMM_PRE();

    #pragma unroll
    for (int mi = 0; mi < 4; ++mi)
        #pragma unroll
        for (int ni = 0; ni < 4; ++ni)
            #pragma unroll
            for (int r = 0; r < 4; ++r) {
                int row = rowBase + wr * 64 + mi * 16 + quad * 4 + r;
                int col = colBase + wc * 64 + ni * 16 + cl;
                Cout[(size_t)row * N + col] = acc[mi][ni][r];
            }
}

// ---------------- flash attention, chunk-local causal (TRANSPOSED) ----------------
// R10 transposed compute (S^T = K Q^T, O^T = V^T P^T; lane owns one q-row;
// P^T register-resident) + PERSISTENT-BALANCED scheduling: grid 512 blocks
// (exactly 2/CU); each block processes q-blocks qi=p and qi=15-p -> 17 tiles
// per block uniformly, zero occupancy tail.

#define ATTN_STAGE(BUF, T)                                                   \
    {                                                                        \
        const int kb2_ = (T) * 128;                                          \
        _Pragma("unroll")                                                    \
        for (int j = 0; j < 4; ++j) {                                        \
            int s = j * 256 + tid;                                           \
            int row = s >> 3;                                                \
            int c = (s & 7) ^ (row & 7);                                     \
            gl_lds16(Kg + (size_t)(kb2_ + row) * 2048 + c * 8, &BUF[s * 8]); \
        }                                                                    \
        _Pragma("unroll")                                                    \
        for (int j = 0; j < 4; ++j) {                                        \
            int s = j * 256 + tid;                                           \
            int d = s >> 4;                                                  \
            int c = (s & 15) ^ (d & 15);                                     \
            gl_lds16(VTg + (size_t)d * CHUNK + kb2_ + c * 8,                 \
                     &BUF[8192 + s * 8]);                                    \
        }                                                                    \
    }

#define ATTN_COMPUTE(BUF, T)                                                  \
    {                                                                         \
        const int kb_ = (T) * 128;                                            \
        const bool last_ = ((T) == qi);                                       \
        _Pragma("unroll")                                                     \
        for (int st = 0; st < 2; ++st) {                                      \
            const int sb = s0 + st * 16;                                      \
            const int qrow = sb + cl;                                         \
            f32x4 sa[8];                                                      \
            _Pragma("unroll")                                                 \
            for (int kt = 0; kt < 8; ++kt) {                                  \
                int key16 = kt * 16 + cl;                                     \
                bf16x8 k0 = *(const bf16x8*)(&BUF[(key16 * 8 + (quad ^ (cl & 7))) * 8]);       \
                bf16x8 k1 = *(const bf16x8*)(&BUF[(key16 * 8 + ((4 + quad) ^ (cl & 7))) * 8]); \
                sa[kt] = __builtin_amdgcn_mfma_f32_16x16x32_bf16(k0, qf[st][0],                \
                             (f32x4){0.f, 0.f, 0.f, 0.f}, 0, 0, 0);           \
                sa[kt] = __builtin_amdgcn_mfma_f32_16x16x32_bf16(k1, qf[st][1], sa[kt], 0, 0, 0); \
            }                                                                 \
            if (last_) {                                                      \
                _Pragma("unroll")                                             \
                for (int kt = 0; kt < 8; ++kt) {                              \
                    int kbase = kb_ + kt * 16 + quad * 4;                     \
                    _Pragma("unroll")                                         \
                    for (int r = 0; r < 4; ++r)                               \
                        if (kbase + r > qrow) sa[kt][r] = -3.0e38f;           \
                }                                                             \
            }                                                                 \
            float mx = fmaxf(fmaxf(sa[0][0], sa[0][1]), fmaxf(sa[0][2], sa[0][3])); \
            _Pragma("unroll")                                                 \
            for (int kt = 1; kt < 8; ++kt)                                    \
                mx = fmaxf(mx, fmaxf(fmaxf(sa[kt][0], sa[kt][1]),             \
                                     fmaxf(sa[kt][2], sa[kt][3])));           \
            mx = fmaxf(mx, __shfl_xor(mx, 16));                               \
            mx = fmaxf(mx, __shfl_xor(mx, 32));                               \
            float mnew = fmaxf(m2[st], mx);                                   \
            float alpha = __builtin_amdgcn_exp2f((m2[st] - mnew) * cs);       \
            float nm = mnew * cs;                                             \
            m2[st] = mnew;                                                    \
            l2[st] *= alpha;                                                  \
            _Pragma("unroll")                                                 \
            for (int dt = 0; dt < 4; ++dt)                                    \
                _Pragma("unroll")                                             \
                for (int r = 0; r < 4; ++r) o_acc[st][dt][r] *= alpha;        \
            _Pragma("unroll")                                                 \
            for (int kt = 0; kt < 8; ++kt)                                    \
                _Pragma("unroll")                                             \
                for (int r = 0; r < 4; ++r)                                   \
                    sa[kt][r] = __builtin_amdgcn_exp2f(__builtin_fmaf(sa[kt][r], cs, -nm)); \
            bf16x8 pfr[4];                                                    \
            _Pragma("unroll")                                                 \
            for (int g = 0; g < 4; ++g) {                                     \
                uint4 pk;                                                     \
                pk.x = pkbf(sa[2 * g][0], sa[2 * g][1]);                      \
                pk.y = pkbf(sa[2 * g][2], sa[2 * g][3]);                      \
                pk.z = pkbf(sa[2 * g + 1][0], sa[2 * g + 1][1]);              \
                pk.w = pkbf(sa[2 * g + 1][2], sa[2 * g + 1][3]);              \
                pfr[g] = __builtin_bit_cast(bf16x8, pk);                      \
            }                                                                 \
            f32x4 rs = (f32x4){0.f, 0.f, 0.f, 0.f};                           \
            _Pragma("unroll")                                                 \
            for (int g = 0; g < 4; ++g)                                       \
                rs = __builtin_amdgcn_mfma_f32_16x16x32_bf16(ones, pfr[g], rs, 0, 0, 0); \
            l2[st] += rs[0];                                                  \
            _Pragma("unroll")                                                 \
            for (int dt = 0; dt < 4; ++dt) {                                  \
                _Pragma("unroll")                                             \
                for (int g = 0; g < 4; ++g) {                                 \
                    int c0 = 4 * g + (quad >> 1);                             \
                    int base = (dt * 16 + cl) * 16;                           \
                    int q4 = (quad & 1) * 4;                                  \
                    short4 va = *(const short4*)(&BUF[8192 + (base + (c0 ^ cl)) * 8 + q4]);       \
                    short4 vb = *(const short4*)(&BUF[8192 + (base + ((c0 + 2) ^ cl)) * 8 + q4]); \
                    bf16x8 vf = {va.x, va.y, va.z, va.w, vb.x, vb.y, vb.z, vb.w};                 \
                    o_acc[st][dt] = __builtin_amdgcn_mfma_f32_16x16x32_bf16(vf, pfr[g], o_acc[st][dt], 0, 0, 0); \
                }                                                             \
            }                                                                 \
        }                                                                     \
    }

__global__ __launch_bounds__(256, 2) void attn_kernel(const short* __restrict__ QK,
                                                      const short* __restrict__ VT,
                                                      short* __restrict__ O) {
    __shared__ __align__(16) short KVa[16384];  // K: 0..8191, V: 8192..16383
    __shared__ __align__(16) short KVb[16384];
    const int tid  = threadIdx.x;
    const int lane = tid & 63;
    const int w    = tid >> 6;
    const int quad = lane >> 4;
    const int cl   = lane & 15;
    const int h = blockIdx.z;
    const int n = blockIdx.y;
    const int qa = (blockIdx.x + blockIdx.y + blockIdx.z) & 7;  // phase-A q-block

    const short* Qg  = QK + (size_t)n * CHUNK * 2048 + h * HDIM;
    const short* Kg  = QK + (size_t)n * CHUNK * 2048 + 1024 + h * HDIM;
    const short* VTg = VT + (size_t)(h * NCHUNK + n) * HDIM * CHUNK;

    bf16x8 ones;
    #pragma unroll
    for (int i = 0; i < 8; ++i) ones[i] = (short)0x3F80;

    const float cs = 0.18033688011f;  // log2(e)/sqrt(64)

    for (int ph = 0; ph < 2; ++ph) {
        const int qi = ph ? 15 - qa : qa;      // pair sums to 17 tiles: uniform
        const int qb0 = qi * 128;
        const int s0  = qb0 + w * 32;

        bf16x8 qf[2][2];
        #pragma unroll
        for (int st = 0; st < 2; ++st)
            #pragma unroll
            for (int hf = 0; hf < 2; ++hf)
                qf[st][hf] = *(const bf16x8*)(Qg + (size_t)(s0 + st * 16 + cl) * 2048 + hf * 32 + quad * 8);

        float m2[2], l2[2];
        f32x4 o_acc[2][4];
        #pragma unroll
        for (int st = 0; st < 2; ++st) {
            m2[st] = -3.0e38f;
            l2[st] = 0.f;
            #pragma unroll
            for (int dt = 0; dt < 4; ++dt) o_acc[st][dt] = (f32x4){0.f, 0.f, 0.f, 0.f};
        }

        const int ntiles = qi + 1;

        if (ph) __syncthreads();  // all waves done with prev phase's buffers
        ATTN_STAGE(KVa, 0);
        int t = 0;
        for (;;) {
            __syncthreads();  // KVa staged; readers of KVb done
            if (t + 1 < ntiles) ATTN_STAGE(KVb, t + 1);
            ATTN_COMPUTE(KVa, t);
            if (++t >= ntiles) break;
            __syncthreads();  // KVb staged; readers of KVa done
            if (t + 1 < ntiles) ATTN_STAGE(KVa, t + 1);
            ATTN_COMPUTE(KVb, t);
            if (++t >= ntiles) break;
        }

        // epilogue: O^T regs -> O[q][d], lane owns q = sb+cl
        #pragma unroll
        for (int st = 0; st < 2; ++st) {
            float linv = __builtin_amdgcn_rcpf(l2[st]);
            size_t rowoff = ((size_t)n * CHUNK + s0 + st * 16 + cl) * D_MODEL + h * HDIM;
            #pragma unroll
            for (int dt = 0; dt < 4; ++dt) {
                short4 o;
                o.x = f2bf(o_acc[st][dt][0] * linv);
                o.y = f2bf(o_acc[st][dt][1] * linv);
                o.z = f2bf(o_acc[st][dt][2] * linv);
                o.w = f2bf(o_acc[st][dt][3] * linv);
                *(short4*)(O + rowoff + dt * 16 + quad * 4) = o;
            }
        }
    }
}

extern "C" void kernel_launch(void* const* d_in, const int* in_sizes, int n_in,
                              void* d_out, int out_size, void* d_ws, size_t ws_size,
                              hipStream_t stream) {
    const float* hs = (const float*)d_in[0];
    const float* Wq = (const float*)d_in[1];
    const float* Wk = (const float*)d_in[2];
    const float* Wv = (const float*)d_in[3];
    const float* Wo = (const float*)d_in[4];
    float* out = (float*)d_out;

    char* ws = (char*)d_ws;
    const size_t MB = 1024 * 1024;
    short* Xbf  = (short*)(ws);              // 16 MB  [8192][1024]
    short* QKb  = (short*)(ws + 16 * MB);    // 32 MB  [8192][2048]  (Q | K)
    short* VT   = (short*)(ws + 48 * MB);    // 16 MB  [h][n][d][key]
    short* Abf  = (short*)(ws + 64 * MB);    // 16 MB  [8192][1024]
    short* Wqkv = (short*)(ws + 80 * MB);    //  6 MB  [3072][1024]
    short* Wob  = (short*)(ws + 86 * MB);    //  2 MB

    const int nHS = SEQ * D_MODEL;
    cvt_f32_bf16<<<nHS / 1024, 256, 0, stream>>>(hs, Xbf, nHS);
    cvt_w4<<<4096, 256, 0, stream>>>(Wq, Wk, Wv, Wo, Wqkv, Wob);

    gemm_qkv<<<dim3(24, 64), 256, 0, stream>>>(Xbf, Wqkv, QKb, VT);

    attn_kernel<<<dim3(8, NCHUNK, NHEADS), 256, 0, stream>>>(QKb, VT, Abf);

    gemm_out<<<dim3(8, 64), 256, 0, stream>>>(Abf, Wob, out, SEQ, D_MODEL, D_MODEL);
}